// Round 10
// baseline (162.153 us; speedup 1.0000x reference)
//
#include <hip/hip_runtime.h>

typedef float f32x4 __attribute__((ext_vector_type(4)));
typedef short s16x8 __attribute__((ext_vector_type(8)));
typedef unsigned short u16;
typedef u16 u16x4v __attribute__((ext_vector_type(4)));
typedef u16 u16x8v __attribute__((ext_vector_type(8)));

#define NB 4
#define NN 2048
#define DI 512
#define DOUTC 512
#define KP 3

__device__ __forceinline__ u16 f2b(float f) {
  unsigned u = __builtin_bit_cast(unsigned, f);
  unsigned r = u + 0x7fffu + ((u >> 16) & 1u);
  return (u16)(r >> 16);
}

// ---------------- prep kernels ----------------
__global__ void prep_uv(const float* __restrict__ Wv, const float* __restrict__ aw,
                        const float* __restrict__ bk, float* u, float* v, float* bsum) {
  int c = blockIdx.x * blockDim.x + threadIdx.x;
  if (c >= DI) return;
  float a1 = 0.f, a2 = 0.f;
  const float* row = Wv + (size_t)c * DOUTC;
  for (int d = 0; d < DOUTC; ++d) {
    float w = row[d];
    a1 += w * aw[d];
    a2 += w * aw[DOUTC + d];
  }
  u[c] = a1; v[c] = a2;
  bsum[c] = bk[c] + bk[DOUTC + c] + bk[2 * DOUTC + c];
}

__global__ void prep_cc(const float* __restrict__ bv, const float* __restrict__ aw,
                        const float* __restrict__ ab, float* cc) {
  int l = threadIdx.x;
  float s = 0.f;
  for (int d = l; d < DOUTC; d += 64) s += bv[d] * (aw[d] + aw[DOUTC + d]);
  for (int o = 32; o; o >>= 1) s += __shfl_down(s, o);
  if (l == 0) cc[0] = s + ab[0];
}

// sj[b,i] = X[b,i,:].u ; si[b,i] = X[b,i,:].v   (one wave per row, f32 inputs)
__global__ void sjsi_kernel(const float* __restrict__ X, const float* __restrict__ u,
                            const float* __restrict__ v, float* sj, float* si) {
  int wid = threadIdx.x >> 6, lane = threadIdx.x & 63;
  int row = blockIdx.x * 4 + wid;
  const f32x4* xr = (const f32x4*)(X + (size_t)row * DI);
  const f32x4* ur = (const f32x4*)u;
  const f32x4* vr = (const f32x4*)v;
  float a1 = 0.f, a2 = 0.f;
#pragma unroll
  for (int t = 0; t < 2; ++t) {
    int f4 = lane + 64 * t;
    f32x4 x = xr[f4], uu = ur[f4], vv = vr[f4];
    a1 += x[0]*uu[0] + x[1]*uu[1] + x[2]*uu[2] + x[3]*uu[3];
    a2 += x[0]*vv[0] + x[1]*vv[1] + x[2]*vv[2] + x[3]*vv[3];
  }
  for (int o = 32; o; o >>= 1) { a1 += __shfl_down(a1, o); a2 += __shfl_down(a2, o); }
  if (!lane) { sj[row] = a1; si[row] = a2; }
}

// tiled transpose -> bf16; optionally also emits the non-transposed bf16 copy.
// per slice: in R x C -> out C x R (and out2 R x C).  grid=(C/64, R/64, slices)
template <typename TI>
__global__ void trans_bf16_k(const TI* __restrict__ in, u16* __restrict__ out,
                             u16* __restrict__ out2, int R, int C) {
  __shared__ u16 tile[64][65];
  const TI* inS = in + (size_t)blockIdx.z * R * C;
  u16* outS = out + (size_t)blockIdx.z * R * C;
  int r0 = blockIdx.y * 64, c0 = blockIdx.x * 64;
  int t = threadIdx.x;
#pragma unroll
  for (int p = 0; p < 4; ++p) {
    int g = t + p * 256;
    int r = g >> 4, c4 = (g & 15) << 2;
    const TI* src = inS + (size_t)(r0 + r) * C + c0 + c4;
    u16x4v bv4;
    if constexpr (sizeof(TI) == 4) {
      f32x4 x = *(const f32x4*)src;
      bv4[0] = f2b(x[0]); bv4[1] = f2b(x[1]); bv4[2] = f2b(x[2]); bv4[3] = f2b(x[3]);
    } else {
      bv4 = *(const u16x4v*)src;
    }
    tile[r][c4+0] = bv4[0]; tile[r][c4+1] = bv4[1];
    tile[r][c4+2] = bv4[2]; tile[r][c4+3] = bv4[3];
    if (out2) {
      *(u16x4v*)(out2 + (size_t)blockIdx.z * R * C + (size_t)(r0 + r) * C + c0 + c4) = bv4;
    }
  }
  __syncthreads();
#pragma unroll
  for (int p = 0; p < 4; ++p) {
    int g = t + p * 256;
    int oc = g >> 4, o4 = (g & 15) << 2;
    u16x4v wv;
    wv[0] = tile[o4+0][oc]; wv[1] = tile[o4+1][oc];
    wv[2] = tile[o4+2][oc]; wv[3] = tile[o4+3][oc];
    *(u16x4v*)(outS + (size_t)(c0 + oc) * R + r0 + o4) = wv;
  }
}

// one wave per row: denom + transition (bf16), alpha kept in registers (32 VGPR).
__global__ void tmat_kernel(const float* __restrict__ Aa, const float* __restrict__ sj,
                            const float* __restrict__ si, const float* __restrict__ ccp,
                            u16* __restrict__ T, int rowbase) {
  int wid = threadIdx.x >> 6, lane = threadIdx.x & 63;
  int lr = blockIdx.x * 4 + wid;
  int gi = rowbase + lr;
  int b = gi >> 11;
  float siv = si[gi] + ccp[0];
  const f32x4* Arow = (const f32x4*)(Aa + (size_t)gi * NN);
  const f32x4* sjr = (const f32x4*)(sj + (size_t)b * NN);
  f32x4 al[8];
  float sum = 0.f;
#pragma unroll
  for (int t = 0; t < 8; ++t) {
    int f4 = lane + 64 * t;
    f32x4 a = Arow[f4];
    f32x4 s = sjr[f4];
#pragma unroll
    for (int j = 0; j < 4; ++j) {
      float e = s[j] + siv;
      e = e > 0.f ? e : 0.2f * e;
      al[t][j] = a[j] * __expf(e);
      sum += al[t][j];
    }
  }
#pragma unroll
  for (int o = 1; o < 64; o <<= 1) sum += __shfl_xor(sum, o);
  float rden = 1.0f / (sum + 1e-12f);
  u16* Trow = T + (size_t)lr * NN;
#pragma unroll
  for (int t = 0; t < 8; ++t) {
    int f4 = lane + 64 * t;
    u16x4v o4;
#pragma unroll
    for (int j = 0; j < 4; ++j) o4[j] = f2b(al[t][j] * rden);
    *(u16x4v*)(Trow + 4 * f4) = o4;
  }
}

// ---- GEMM: 128x64 tile, 4 waves, BK=64, 3-buffer counted-vmcnt(6) pipeline
// (round-6 proven), inner loop phase-split (T3) + setprio (T5):
// per K-step 2 phases of {half-stage || 6 ds_read; lgkm; barrier; 8 MFMA}. ----
struct GemmP {
  const u16 *A0, *A1, *A2;   // row-major M x Kc (per source)
  const u16 *B0, *B1, *B2;   // row-major N x Kc  (B transposed)
  const float* bias;
  void* out;
  u16* outT;                 // optional transposed bf16 output (ldOT = M-dim)
  int ldA, ldB, ldO, ldOT;
  size_t batchA, batchB, batchOut, batchOutT;
};

__device__ __forceinline__ void gload16(const u16* g, const u16* l) {
  __builtin_amdgcn_global_load_lds((const __attribute__((address_space(1))) void*)g,
                                   (__attribute__((address_space(3))) void*)l, 16, 0, 0);
}

// chunk-XOR swizzled LDS: global (row, c8) stored at LDS chunk row*8 + (c8 ^ (row&7)).
template <int NSRC, int KT, bool OBF, bool OTR>
__launch_bounds__(256)
__global__ void gemm_k(GemmP p) {
  __shared__ u16 As[3][128 * 64];
  __shared__ u16 Bs[3][64 * 64];
  int tid = threadIdx.x;
  int lane = tid & 63;
  int w = tid >> 6;
  int wr = w >> 1, wc = w & 1;
  int bm = blockIdx.x, bn = blockIdx.y, bz = blockIdx.z;
  const u16* Alist[3] = {p.A0, p.A1, p.A2};
  const u16* Blist[3] = {p.B0, p.B1, p.B2};
  int rof = lane & 15, ksel = lane >> 4, sw = lane & 7;
  int wub = (tid & 192) * 8;  // wave-uniform chunk base (elems) within a 256-chunk group
  f32x4 acc[4][2] = {};

  // h = 0: A-chunks q=0,1 + B-chunk q=0;  h = 1: A-chunks q=2,3 + B-chunk q=1.
  auto stageHalf = [&](int t, int buf, int h) {
    int s = t / KT;
    int k0 = (t - s * KT) * 64;
    const u16* Ag = Alist[s] + (size_t)bz * p.batchA + (size_t)bm * 128 * p.ldA;
    const u16* Bg = Blist[s] + (size_t)bz * p.batchB + (size_t)bn * 64 * p.ldB;
#pragma unroll
    for (int qq = 0; qq < 2; ++qq) {
      int q = h * 2 + qq;
      int ch = q * 256 + tid;
      int row = ch >> 3;
      int c8 = (ch & 7) ^ (row & 7);
      gload16(Ag + (size_t)row * p.ldA + k0 + c8 * 8, &As[buf][0] + q * 2048 + wub);
    }
    {
      int ch = h * 256 + tid;
      int row = ch >> 3;
      int c8 = (ch & 7) ^ (row & 7);
      gload16(Bg + (size_t)row * p.ldB + k0 + c8 * 8, &Bs[buf][0] + h * 2048 + wub);
    }
  };

  constexpr int TOT = NSRC * KT;
  stageHalf(0, 0, 0); stageHalf(0, 0, 1);
  stageHalf(1, 1, 0); stageHalf(1, 1, 1);
  asm volatile("s_waitcnt vmcnt(6)" ::: "memory");
  __builtin_amdgcn_s_barrier();
  __builtin_amdgcn_sched_barrier(0);

  int bufc = 0;
  for (int t = 0; t < TOT; ++t) {
    int nb = t + 2;
    int nslot = bufc == 0 ? 2 : bufc - 1;
    const u16* Asb = &As[bufc][0];
    const u16* Bsb = &Bs[bufc][0];
    // ---------------- phase 0 (kk = 0) ----------------
    if (nb < TOT) stageHalf(nb, nslot, 0);
    s16x8 af0[4], bf0[2];
    {
      int csw = (ksel ^ sw) * 8;
#pragma unroll
      for (int mf = 0; mf < 4; ++mf)
        af0[mf] = *(const s16x8*)(Asb + (wr * 64 + mf * 16 + rof) * 64 + csw);
#pragma unroll
      for (int nf = 0; nf < 2; ++nf)
        bf0[nf] = *(const s16x8*)(Bsb + (wc * 32 + nf * 16 + rof) * 64 + csw);
    }
    asm volatile("s_waitcnt lgkmcnt(0)" ::: "memory");
    __builtin_amdgcn_s_barrier();
    __builtin_amdgcn_sched_barrier(0);
    __builtin_amdgcn_s_setprio(1);
#pragma unroll
    for (int mf = 0; mf < 4; ++mf)
#pragma unroll
      for (int nf = 0; nf < 2; ++nf)
        acc[mf][nf] = __builtin_amdgcn_mfma_f32_16x16x32_bf16(af0[mf], bf0[nf], acc[mf][nf], 0, 0, 0);
    __builtin_amdgcn_s_setprio(0);
    __builtin_amdgcn_sched_barrier(0);
    // ---------------- phase 1 (kk = 1) ----------------
    if (nb < TOT) stageHalf(nb, nslot, 1);
    s16x8 af1[4], bf1[2];
    {
      int csw = ((4 + ksel) ^ sw) * 8;
#pragma unroll
      for (int mf = 0; mf < 4; ++mf)
        af1[mf] = *(const s16x8*)(Asb + (wr * 64 + mf * 16 + rof) * 64 + csw);
#pragma unroll
      for (int nf = 0; nf < 2; ++nf)
        bf1[nf] = *(const s16x8*)(Bsb + (wc * 32 + nf * 16 + rof) * 64 + csw);
    }
    if (nb < TOT) {
      asm volatile("s_waitcnt vmcnt(6)" ::: "memory");   // stage(t+1) landed; t+2 in flight
    } else if (t + 1 < TOT) {
      asm volatile("s_waitcnt vmcnt(0)" ::: "memory");   // tail: drain last stage
    }
    asm volatile("s_waitcnt lgkmcnt(0)" ::: "memory");
    if (t + 1 < TOT) __builtin_amdgcn_s_barrier();
    __builtin_amdgcn_sched_barrier(0);
    __builtin_amdgcn_s_setprio(1);
#pragma unroll
    for (int mf = 0; mf < 4; ++mf)
#pragma unroll
      for (int nf = 0; nf < 2; ++nf)
        acc[mf][nf] = __builtin_amdgcn_mfma_f32_16x16x32_bf16(af1[mf], bf1[nf], acc[mf][nf], 0, 0, 0);
    __builtin_amdgcn_s_setprio(0);
    __builtin_amdgcn_sched_barrier(0);
    bufc = bufc + 1; if (bufc == 3) bufc = 0;
  }

  int rb = bm * 128 + wr * 64, cb = bn * 64 + wc * 32;
  int rsub = ksel << 2, csub = rof;
  if constexpr (OBF) {
    u16* o = (u16*)p.out + (size_t)bz * p.batchOut;
    u16* oT = OTR ? p.outT + (size_t)bz * p.batchOutT : nullptr;
#pragma unroll
    for (int mf = 0; mf < 4; ++mf)
#pragma unroll
      for (int nf = 0; nf < 2; ++nf) {
        int cidx = cb + nf * 16 + csub;
        u16x4v tv;
#pragma unroll
        for (int r = 0; r < 4; ++r) {
          tv[r] = f2b(acc[mf][nf][r]);
          o[(size_t)(rb + mf * 16 + rsub + r) * p.ldO + cidx] = tv[r];
        }
        if constexpr (OTR) {
          *(u16x4v*)(oT + (size_t)cidx * p.ldOT + rb + mf * 16 + rsub) = tv;
        }
      }
  } else {
    float* o = (float*)p.out + (size_t)bz * p.batchOut;
#pragma unroll
    for (int nf = 0; nf < 2; ++nf) {
      int cidx = cb + nf * 16 + csub;
      float bv_ = p.bias[cidx];
#pragma unroll
      for (int mf = 0; mf < 4; ++mf)
#pragma unroll
        for (int r = 0; r < 4; ++r) {
          float val = acc[mf][nf][r] + bv_;
          o[(size_t)(rb + mf * 16 + rsub + r) * p.ldO + cidx] = val > 0.f ? val : 0.f;
        }
    }
  }
}

// ---------------- launch ----------------
extern "C" void kernel_launch(void* const* d_in, const int* in_sizes, int n_in,
                              void* d_out, int out_size, void* d_ws, size_t ws_size,
                              hipStream_t stream) {
  const float* X  = (const float*)d_in[0];
  const float* A  = (const float*)d_in[1];
  const float* Wv = (const float*)d_in[2];
  const float* bv = (const float*)d_in[3];
  const float* aw = (const float*)d_in[4];
  const float* ab = (const float*)d_in[5];
  const float* Wk = (const float*)d_in[6];
  const float* bk = (const float*)d_in[7];
  float* out = (float*)d_out;

  char* ws = (char*)d_ws;
  size_t off = 0;
  auto alloc = [&](size_t bytes) -> void* {
    void* p = (void*)(ws + off);
    off = (off + bytes + 255) & ~(size_t)255;
    return p;
  };
  float* u    = (float*)alloc(DI * 4);
  float* v    = (float*)alloc(DI * 4);
  float* cc   = (float*)alloc(256);
  float* bsum = (float*)alloc(DOUTC * 4);
  float* sj   = (float*)alloc((size_t)NB * NN * 4);
  float* si   = (float*)alloc((size_t)NB * NN * 4);
  u16* WkT  = (u16*)alloc((size_t)KP * DI * DOUTC * 2);
  u16* Xb   = (u16*)alloc((size_t)NB * NN * DI * 2);
  u16* XbT  = (u16*)alloc((size_t)NB * NN * DI * 2);
  u16* X1b  = (u16*)alloc((size_t)NB * NN * DOUTC * 2);
  u16* X1bT = (u16*)alloc((size_t)NB * NN * DOUTC * 2);
  u16* X2b  = (u16*)alloc((size_t)NB * NN * DOUTC * 2);
  size_t fixedEnd = off;
  int G = 4;
  while (G > 1 && fixedEnd + (size_t)G * NN * NN * 2 > ws_size) G >>= 1;
  u16* Tb = (u16*)alloc((size_t)G * NN * NN * 2);

  prep_uv<<<2, 256, 0, stream>>>(Wv, aw, bk, u, v, bsum);
  prep_cc<<<1, 64, 0, stream>>>(bv, aw, ab, cc);
  trans_bf16_k<float><<<dim3(8, 8, 3), 256, 0, stream>>>(Wk, WkT, nullptr, 512, 512);
  // X: one read -> XbT (transposed bf16) + Xb (row-major bf16)
  trans_bf16_k<float><<<dim3(8, 32, 4), 256, 0, stream>>>(X, XbT, Xb, NN, DI);
  sjsi_kernel<<<NB * NN / 4, 256, 0, stream>>>(X, u, v, sj, si);

  for (int g0 = 0; g0 < NB; g0 += G) {
    tmat_kernel<<<G * NN / 4, 256, 0, stream>>>(A, sj, si, cc, Tb, g0 * NN);

    GemmP p1{};
    p1.A0 = p1.A1 = p1.A2 = Tb;
    p1.B0 = p1.B1 = p1.B2 = XbT + (size_t)g0 * DI * NN;
    p1.bias = nullptr;
    p1.out = X1b + (size_t)g0 * NN * DOUTC;
    p1.outT = X1bT + (size_t)g0 * DOUTC * NN;
    p1.ldA = NN; p1.ldB = NN; p1.ldO = DOUTC; p1.ldOT = NN;
    p1.batchA = (size_t)NN * NN; p1.batchB = (size_t)DI * NN;
    p1.batchOut = (size_t)NN * DOUTC; p1.batchOutT = (size_t)DOUTC * NN;
    gemm_k<1, 32, true, true><<<dim3(16, 8, G), 256, 0, stream>>>(p1);

    GemmP p2 = p1;
    p2.B0 = p2.B1 = p2.B2 = X1bT + (size_t)g0 * DOUTC * NN;
    p2.out = X2b + (size_t)g0 * NN * DOUTC;
    p2.outT = nullptr;
    gemm_k<1, 32, true, false><<<dim3(16, 8, G), 256, 0, stream>>>(p2);
  }

  GemmP p3{};
  p3.A0 = Xb; p3.A1 = X1b; p3.A2 = X2b;
  p3.B0 = WkT; p3.B1 = WkT + (size_t)DI * DOUTC; p3.B2 = WkT + (size_t)2 * DI * DOUTC;
  p3.bias = bsum; p3.out = out; p3.outT = nullptr;
  p3.ldA = DI; p3.ldB = DI; p3.ldO = DOUTC; p3.ldOT = 0;
  p3.batchA = 0; p3.batchB = 0; p3.batchOut = 0; p3.batchOutT = 0;
  gemm_k<3, 8, false, false><<<dim3(64, 8, 1), 256, 0, stream>>>(p3);
}

// Round 11
// 141.594 us; speedup vs baseline: 1.1452x; 1.1452x over previous
//
#include <hip/hip_runtime.h>

typedef float f32x4 __attribute__((ext_vector_type(4)));
typedef short s16x8 __attribute__((ext_vector_type(8)));
typedef unsigned short u16;
typedef u16 u16x4v __attribute__((ext_vector_type(4)));
typedef u16 u16x8v __attribute__((ext_vector_type(8)));

#define NB 4
#define NN 2048
#define DI 512
#define DOUTC 512
#define KP 3

__device__ __forceinline__ u16 f2b(float f) {
  unsigned u = __builtin_bit_cast(unsigned, f);
  unsigned r = u + 0x7fffu + ((u >> 16) & 1u);
  return (u16)(r >> 16);
}
__device__ __forceinline__ float b2f(u16 h) {
  unsigned u = (unsigned)h << 16;
  return __builtin_bit_cast(float, u);
}

// ---------------- prep (merged): blocks 0-1 -> u,v,bsum ; block 2 -> cc ----
__global__ void prep_all(const float* __restrict__ Wv, const float* __restrict__ aw,
                         const float* __restrict__ bk, const float* __restrict__ bv,
                         const float* __restrict__ ab,
                         float* u, float* v, float* bsum, float* cc) {
  if (blockIdx.x < 2) {
    int c = blockIdx.x * 256 + threadIdx.x;
    float a1 = 0.f, a2 = 0.f;
    const float* row = Wv + (size_t)c * DOUTC;
    for (int d = 0; d < DOUTC; ++d) {
      float w = row[d];
      a1 += w * aw[d];
      a2 += w * aw[DOUTC + d];
    }
    u[c] = a1; v[c] = a2;
    bsum[c] = bk[c] + bk[DOUTC + c] + bk[2 * DOUTC + c];
  } else if (threadIdx.x < 64) {
    int l = threadIdx.x;
    float s = 0.f;
    for (int d = l; d < DOUTC; d += 64) s += bv[d] * (aw[d] + aw[DOUTC + d]);
    for (int o = 32; o; o >>= 1) s += __shfl_down(s, o);
    if (l == 0) cc[0] = s + ab[0];
  }
}

// sj[b,i] = X[b,i,:].u ; si[b,i] = X[b,i,:].v   (one wave per row, f32 inputs)
__global__ void sjsi_kernel(const float* __restrict__ X, const float* __restrict__ u,
                            const float* __restrict__ v, float* sj, float* si) {
  int wid = threadIdx.x >> 6, lane = threadIdx.x & 63;
  int row = blockIdx.x * 4 + wid;
  const f32x4* xr = (const f32x4*)(X + (size_t)row * DI);
  const f32x4* ur = (const f32x4*)u;
  const f32x4* vr = (const f32x4*)v;
  float a1 = 0.f, a2 = 0.f;
#pragma unroll
  for (int t = 0; t < 2; ++t) {
    int f4 = lane + 64 * t;
    f32x4 x = xr[f4], uu = ur[f4], vv = vr[f4];
    a1 += x[0]*uu[0] + x[1]*uu[1] + x[2]*uu[2] + x[3]*uu[3];
    a2 += x[0]*vv[0] + x[1]*vv[1] + x[2]*vv[2] + x[3]*vv[3];
  }
  for (int o = 32; o; o >>= 1) { a1 += __shfl_down(a1, o); a2 += __shfl_down(a2, o); }
  if (!lane) { sj[row] = a1; si[row] = a2; }
}

// elementwise f32 -> bf16 (8 per thread)
__global__ void cvt_bf16(const float* __restrict__ in, u16* __restrict__ out, int n8) {
  int i = blockIdx.x * blockDim.x + threadIdx.x;
  if (i >= n8) return;
  const f32x4* p = (const f32x4*)in + (size_t)i * 2;
  f32x4 a = p[0], b = p[1];
  u16x8v r;
  r[0]=f2b(a[0]); r[1]=f2b(a[1]); r[2]=f2b(a[2]); r[3]=f2b(a[3]);
  r[4]=f2b(b[0]); r[5]=f2b(b[1]); r[6]=f2b(b[2]); r[7]=f2b(b[3]);
  ((u16x8v*)out)[i] = r;
}

// tiled transpose -> bf16 (for Wk). per slice: in R x C -> out C x R.
template <typename TI>
__global__ void trans_bf16_k(const TI* __restrict__ in, u16* __restrict__ out,
                             int R, int C) {
  __shared__ u16 tile[64][65];
  const TI* inS = in + (size_t)blockIdx.z * R * C;
  u16* outS = out + (size_t)blockIdx.z * R * C;
  int r0 = blockIdx.y * 64, c0 = blockIdx.x * 64;
  int t = threadIdx.x;
#pragma unroll
  for (int p = 0; p < 4; ++p) {
    int g = t + p * 256;
    int r = g >> 4, c4 = (g & 15) << 2;
    const TI* src = inS + (size_t)(r0 + r) * C + c0 + c4;
    f32x4 x = *(const f32x4*)src;
    tile[r][c4+0] = f2b(x[0]); tile[r][c4+1] = f2b(x[1]);
    tile[r][c4+2] = f2b(x[2]); tile[r][c4+3] = f2b(x[3]);
  }
  __syncthreads();
#pragma unroll
  for (int p = 0; p < 4; ++p) {
    int g = t + p * 256;
    int oc = g >> 4, o4 = (g & 15) << 2;
    u16x4v wv;
    wv[0] = tile[o4+0][oc]; wv[1] = tile[o4+1][oc];
    wv[2] = tile[o4+2][oc]; wv[3] = tile[o4+3][oc];
    *(u16x4v*)(outS + (size_t)(c0 + oc) * R + r0 + o4) = wv;
  }
}

// one wave per row: denom + transition (bf16), alpha kept in registers (32 VGPR).
__global__ void tmat_kernel(const float* __restrict__ Aa, const float* __restrict__ sj,
                            const float* __restrict__ si, const float* __restrict__ ccp,
                            u16* __restrict__ T, int rowbase) {
  int wid = threadIdx.x >> 6, lane = threadIdx.x & 63;
  int lr = blockIdx.x * 4 + wid;
  int gi = rowbase + lr;
  int b = gi >> 11;
  float siv = si[gi] + ccp[0];
  const f32x4* Arow = (const f32x4*)(Aa + (size_t)gi * NN);
  const f32x4* sjr = (const f32x4*)(sj + (size_t)b * NN);
  f32x4 al[8];
  float sum = 0.f;
#pragma unroll
  for (int t = 0; t < 8; ++t) {
    int f4 = lane + 64 * t;
    f32x4 a = Arow[f4];
    f32x4 s = sjr[f4];
#pragma unroll
    for (int j = 0; j < 4; ++j) {
      float e = s[j] + siv;
      e = e > 0.f ? e : 0.2f * e;
      al[t][j] = a[j] * __expf(e);
      sum += al[t][j];
    }
  }
#pragma unroll
  for (int o = 1; o < 64; o <<= 1) sum += __shfl_xor(sum, o);
  float rden = 1.0f / (sum + 1e-12f);
  u16* Trow = T + (size_t)lr * NN;
#pragma unroll
  for (int t = 0; t < 8; ++t) {
    int f4 = lane + 64 * t;
    u16x4v o4;
#pragma unroll
    for (int j = 0; j < 4; ++j) o4[j] = f2b(al[t][j] * rden);
    *(u16x4v*)(Trow + 4 * f4) = o4;
  }
}

// ---- GEMM: 128x64 tile, 4 waves, BK=64, 3-buffer counted-vmcnt(6) pipeline
// (round-6 HW-validated loop, verbatim). Variants via template flags only:
//   WSEL: blockIdx.z -> (batch = z&3, weight j = z>>2) decode (gemmW)
//   ADD : epilogue adds bf16 addsrc tile
//   OTR : also write transposed bf16 output (gated to j==2 under WSEL) ----
struct GemmP {
  const u16 *A0;             // row-major M x Kc
  const u16 *B0;             // row-major N x Kc (B transposed)
  const u16 *addsrc;         // optional epilogue add (bf16, out-indexed)
  const float* bias;
  void* out;
  u16* outT;                 // optional transposed bf16 output (ldOT = M-dim)
  int ldA, ldB, ldO, ldOT;
  size_t batchA, batchB, batchOut, batchOutT;
};

__device__ __forceinline__ void gload16(const u16* g, const u16* l) {
  __builtin_amdgcn_global_load_lds((const __attribute__((address_space(1))) void*)g,
                                   (__attribute__((address_space(3))) void*)l, 16, 0, 0);
}

// chunk-XOR swizzled LDS: global (row, c8) stored at LDS chunk row*8 + (c8 ^ (row&7)).
template <int KT, bool OBF, bool OTR, bool WSEL, bool ADD>
__launch_bounds__(256)
__global__ void gemm_k(GemmP p) {
  __shared__ u16 As[3][128 * 64];
  __shared__ u16 Bs[3][64 * 64];
  int tid = threadIdx.x;
  int lane = tid & 63;
  int w = tid >> 6;
  int wr = w >> 1, wc = w & 1;
  int bm = blockIdx.x, bn = blockIdx.y, bz = blockIdx.z;
  int rof = lane & 15, ksel = lane >> 4, sw = lane & 7;
  int wub = (tid & 192) * 8;  // wave-uniform chunk base (elems) within a 256-chunk group
  f32x4 acc[4][2] = {};

  int jsel = 0;
  size_t aOff, bOff;
  if constexpr (WSEL) {
    int bb = bz & 3; jsel = bz >> 2;
    aOff = (size_t)bb * p.batchA; bOff = (size_t)jsel * p.batchB;
  } else {
    aOff = (size_t)bz * p.batchA; bOff = (size_t)bz * p.batchB;
  }
  const u16* Agb = p.A0 + aOff + (size_t)bm * 128 * p.ldA;
  const u16* Bgb = p.B0 + bOff + (size_t)bn * 64 * p.ldB;

  auto stage = [&](int t, int buf) {
    int k0 = t * 64;
#pragma unroll
    for (int q = 0; q < 4; ++q) {
      int ch = q * 256 + tid;
      int row = ch >> 3;
      int c8 = (ch & 7) ^ (row & 7);
      gload16(Agb + (size_t)row * p.ldA + k0 + c8 * 8, &As[buf][0] + q * 2048 + wub);
    }
#pragma unroll
    for (int q = 0; q < 2; ++q) {
      int ch = q * 256 + tid;
      int row = ch >> 3;
      int c8 = (ch & 7) ^ (row & 7);
      gload16(Bgb + (size_t)row * p.ldB + k0 + c8 * 8, &Bs[buf][0] + q * 2048 + wub);
    }
  };

  constexpr int TOT = KT;
  stage(0, 0);
  stage(1, 1);
  asm volatile("s_waitcnt vmcnt(6)" ::: "memory");
  __builtin_amdgcn_s_barrier();
  __builtin_amdgcn_sched_barrier(0);

  int bufc = 0;
  for (int t = 0; t < TOT; ++t) {
    int nb = t + 2;
    if (nb < TOT) stage(nb, bufc == 0 ? 2 : bufc - 1);
    const u16* Asb = &As[bufc][0];
    const u16* Bsb = &Bs[bufc][0];
#pragma unroll
    for (int kk = 0; kk < 2; ++kk) {
      int csw = ((kk * 4 + ksel) ^ sw) * 8;
      s16x8 af[4], bfr[2];
#pragma unroll
      for (int mf = 0; mf < 4; ++mf) {
        int r = wr * 64 + mf * 16 + rof;
        af[mf] = *(const s16x8*)(Asb + r * 64 + csw);
      }
#pragma unroll
      for (int nf = 0; nf < 2; ++nf) {
        int r = wc * 32 + nf * 16 + rof;
        bfr[nf] = *(const s16x8*)(Bsb + r * 64 + csw);
      }
#pragma unroll
      for (int mf = 0; mf < 4; ++mf)
#pragma unroll
        for (int nf = 0; nf < 2; ++nf)
          acc[mf][nf] = __builtin_amdgcn_mfma_f32_16x16x32_bf16(af[mf], bfr[nf], acc[mf][nf], 0, 0, 0);
    }
    if (nb < TOT) {
      asm volatile("s_waitcnt vmcnt(6)" ::: "memory");   // stage(t+1) landed; t+2 in flight
    } else if (t + 1 < TOT) {
      asm volatile("s_waitcnt vmcnt(0)" ::: "memory");   // tail: drain last stage
    }
    if (t + 1 < TOT) {
      __builtin_amdgcn_s_barrier();
      __builtin_amdgcn_sched_barrier(0);
    }
    bufc = bufc + 1; if (bufc == 3) bufc = 0;
  }

  int rb = bm * 128 + wr * 64, cb = bn * 64 + wc * 32;
  int rsub = ksel << 2, csub = rof;
  const u16* ad = nullptr;
  if constexpr (ADD) ad = p.addsrc + (size_t)bz * p.batchOut;
  if constexpr (OBF) {
    u16* o = (u16*)p.out + (size_t)bz * p.batchOut;
    bool doT = OTR && (!WSEL || jsel == 2);
    u16* oT = nullptr;
    if (OTR && doT) oT = p.outT + (size_t)(WSEL ? (bz & 3) : bz) * p.batchOutT;
#pragma unroll
    for (int mf = 0; mf < 4; ++mf)
#pragma unroll
      for (int nf = 0; nf < 2; ++nf) {
        int cidx = cb + nf * 16 + csub;
        u16x4v tv;
#pragma unroll
        for (int r = 0; r < 4; ++r) {
          size_t idx = (size_t)(rb + mf * 16 + rsub + r) * p.ldO + cidx;
          float v = acc[mf][nf][r];
          if constexpr (ADD) v += b2f(ad[idx]);
          tv[r] = f2b(v);
          o[idx] = tv[r];
        }
        if (OTR && doT) {
          *(u16x4v*)(oT + (size_t)cidx * p.ldOT + rb + mf * 16 + rsub) = tv;
        }
      }
  } else {
    float* o = (float*)p.out + (size_t)bz * p.batchOut;
#pragma unroll
    for (int nf = 0; nf < 2; ++nf) {
      int cidx = cb + nf * 16 + csub;
      float bv_ = p.bias[cidx];
#pragma unroll
      for (int mf = 0; mf < 4; ++mf)
#pragma unroll
        for (int r = 0; r < 4; ++r) {
          size_t idx = (size_t)(rb + mf * 16 + rsub + r) * p.ldO + cidx;
          float val = acc[mf][nf][r] + bv_;
          if constexpr (ADD) val += b2f(ad[idx]);
          o[idx] = val > 0.f ? val : 0.f;
        }
    }
  }
}

// ---------------- launch ----------------
// Horner form: H = relu( Y0 + T@( Y1 + T@Y2 ) + bsum ),  Yj = X @ Wj
extern "C" void kernel_launch(void* const* d_in, const int* in_sizes, int n_in,
                              void* d_out, int out_size, void* d_ws, size_t ws_size,
                              hipStream_t stream) {
  const float* X  = (const float*)d_in[0];
  const float* A  = (const float*)d_in[1];
  const float* Wv = (const float*)d_in[2];
  const float* bv = (const float*)d_in[3];
  const float* aw = (const float*)d_in[4];
  const float* ab = (const float*)d_in[5];
  const float* Wk = (const float*)d_in[6];
  const float* bk = (const float*)d_in[7];
  float* out = (float*)d_out;

  char* ws = (char*)d_ws;
  size_t off = 0;
  auto alloc = [&](size_t bytes) -> void* {
    void* p = (void*)(ws + off);
    off = (off + bytes + 255) & ~(size_t)255;
    return p;
  };
  float* u    = (float*)alloc(DI * 4);
  float* v    = (float*)alloc(DI * 4);
  float* cc   = (float*)alloc(256);
  float* bsum = (float*)alloc(DOUTC * 4);
  float* sj   = (float*)alloc((size_t)NB * NN * 4);
  float* si   = (float*)alloc((size_t)NB * NN * 4);
  u16* WkT  = (u16*)alloc((size_t)KP * DI * DOUTC * 2);
  u16* Xb   = (u16*)alloc((size_t)NB * NN * DI * 2);
  u16* Y    = (u16*)alloc((size_t)KP * NB * NN * DOUTC * 2);   // [j][b][NN][DOUT]
  u16* Y2T  = (u16*)alloc((size_t)NB * DOUTC * NN * 2);
  u16* Zb   = (u16*)alloc((size_t)NB * NN * DOUTC * 2);
  u16* ZbT  = (u16*)alloc((size_t)NB * DOUTC * NN * 2);
  size_t fixedEnd = off;
  int G = 4;
  while (G > 1 && fixedEnd + (size_t)G * NN * NN * 2 > ws_size) G >>= 1;
  u16* Tb = (u16*)alloc((size_t)G * NN * NN * 2);

  prep_all<<<3, 256, 0, stream>>>(Wv, aw, bk, bv, ab, u, v, bsum, cc);
  trans_bf16_k<float><<<dim3(8, 8, 3), 256, 0, stream>>>(Wk, WkT, 512, 512);
  cvt_bf16<<<2048, 256, 0, stream>>>(X, Xb, NB * NN * DI / 8);
  sjsi_kernel<<<NB * NN / 4, 256, 0, stream>>>(X, u, v, sj, si);

  // Yj = X @ Wj  (j=0..2, all batches; Y2 also written transposed)
  GemmP pw{};
  pw.A0 = Xb; pw.B0 = WkT; pw.addsrc = nullptr; pw.bias = nullptr;
  pw.out = Y; pw.outT = Y2T;
  pw.ldA = DI; pw.ldB = DI; pw.ldO = DOUTC; pw.ldOT = NN;
  pw.batchA = (size_t)NN * DI; pw.batchB = (size_t)DI * DOUTC;
  pw.batchOut = (size_t)NN * DOUTC; pw.batchOutT = (size_t)DOUTC * NN;
  gemm_k<8, true, true, true, false><<<dim3(16, 8, KP * NB), 256, 0, stream>>>(pw);

  for (int g0 = 0; g0 < NB; g0 += G) {
    tmat_kernel<<<G * NN / 4, 256, 0, stream>>>(A, sj, si, cc, Tb, g0 * NN);

    // Z = Y1 + T @ Y2   (bf16 out + transposed out)
    GemmP pa{};
    pa.A0 = Tb;
    pa.B0 = Y2T + (size_t)g0 * DOUTC * NN;
    pa.addsrc = Y + (size_t)(NB + g0) * NN * DOUTC;   // Y1[b]
    pa.bias = nullptr;
    pa.out = Zb + (size_t)g0 * NN * DOUTC;
    pa.outT = ZbT + (size_t)g0 * DOUTC * NN;
    pa.ldA = NN; pa.ldB = NN; pa.ldO = DOUTC; pa.ldOT = NN;
    pa.batchA = (size_t)NN * NN; pa.batchB = (size_t)DOUTC * NN;
    pa.batchOut = (size_t)NN * DOUTC; pa.batchOutT = (size_t)DOUTC * NN;
    gemm_k<32, true, true, false, true><<<dim3(16, 8, G), 256, 0, stream>>>(pa);

    // H = relu( Y0 + T @ Z + bsum )   (f32 out)
    GemmP pb{};
    pb.A0 = Tb;
    pb.B0 = ZbT + (size_t)g0 * DOUTC * NN;
    pb.addsrc = Y + (size_t)g0 * NN * DOUTC;          // Y0[b]
    pb.bias = bsum;
    pb.out = out + (size_t)g0 * NN * DOUTC;
    pb.outT = nullptr;
    pb.ldA = NN; pb.ldB = NN; pb.ldO = DOUTC; pb.ldOT = 0;
    pb.batchA = (size_t)NN * NN; pb.batchB = (size_t)DOUTC * NN;
    pb.batchOut = (size_t)NN * DOUTC; pb.batchOutT = 0;
    gemm_k<32, false, false, false, true><<<dim3(16, 8, G), 256, 0, stream>>>(pb);
  }
}

// Round 12
// 135.038 us; speedup vs baseline: 1.2008x; 1.0486x over previous
//
#include <hip/hip_runtime.h>

typedef float f32x4 __attribute__((ext_vector_type(4)));
typedef short s16x8 __attribute__((ext_vector_type(8)));
typedef unsigned short u16;
typedef u16 u16x4v __attribute__((ext_vector_type(4)));
typedef u16 u16x8v __attribute__((ext_vector_type(8)));

#define NB 4
#define NN 2048
#define DI 512
#define DOUTC 512
#define KP 3
#define KCAT 1536   // 3*512 concatenated K for gemm3

__device__ __forceinline__ u16 f2b(float f) {
  unsigned u = __builtin_bit_cast(unsigned, f);
  unsigned r = u + 0x7fffu + ((u >> 16) & 1u);
  return (u16)(r >> 16);
}

// ---------------- prep (merged): blocks 0-1 -> u,v,bsum ; block 2 -> cc ----
__global__ void prep_all(const float* __restrict__ Wv, const float* __restrict__ aw,
                         const float* __restrict__ bk, const float* __restrict__ bv,
                         const float* __restrict__ ab,
                         float* u, float* v, float* bsum, float* cc) {
  if (blockIdx.x < 2) {
    int c = blockIdx.x * 256 + threadIdx.x;
    float a1 = 0.f, a2 = 0.f;
    const float* row = Wv + (size_t)c * DOUTC;
    for (int d = 0; d < DOUTC; ++d) {
      float w = row[d];
      a1 += w * aw[d];
      a2 += w * aw[DOUTC + d];
    }
    u[c] = a1; v[c] = a2;
    bsum[c] = bk[c] + bk[DOUTC + c] + bk[2 * DOUTC + c];
  } else if (threadIdx.x < 64) {
    int l = threadIdx.x;
    float s = 0.f;
    for (int d = l; d < DOUTC; d += 64) s += bv[d] * (aw[d] + aw[DOUTC + d]);
    for (int o = 32; o; o >>= 1) s += __shfl_down(s, o);
    if (l == 0) cc[0] = s + ab[0];
  }
}

// Wk transpose -> BkT123 [n=512][1536] with k offset z*512.  grid (8,8,3)
__global__ void transWk_k(const float* __restrict__ in, u16* __restrict__ out) {
  __shared__ u16 tile[64][65];
  const float* inS = in + (size_t)blockIdx.z * DI * DOUTC;
  int r0 = blockIdx.y * 64, c0 = blockIdx.x * 64;
  int t = threadIdx.x;
#pragma unroll
  for (int p = 0; p < 4; ++p) {
    int g = t + p * 256;
    int r = g >> 4, c4 = (g & 15) << 2;
    f32x4 x = *(const f32x4*)(inS + (size_t)(r0 + r) * DOUTC + c0 + c4);
    tile[r][c4+0] = f2b(x[0]); tile[r][c4+1] = f2b(x[1]);
    tile[r][c4+2] = f2b(x[2]); tile[r][c4+3] = f2b(x[3]);
  }
  __syncthreads();
#pragma unroll
  for (int p = 0; p < 4; ++p) {
    int g = t + p * 256;
    int oc = g >> 4, o4 = (g & 15) << 2;
    u16x4v wv;
    wv[0] = tile[o4+0][oc]; wv[1] = tile[o4+1][oc];
    wv[2] = tile[o4+2][oc]; wv[3] = tile[o4+3][oc];
    *(u16x4v*)(out + (size_t)(c0 + oc) * KCAT + blockIdx.z * 512 + r0 + o4) = wv;
  }
}

// X transpose + bf16 copy into X123 + fused sj/si partial dots.
// grid (8, 32, NB): c0 = bx*64 (X cols), r0 = by*64 (X rows), z = batch.
__global__ void transX_k(const float* __restrict__ X, u16* __restrict__ XbT,
                         u16* __restrict__ X123,
                         const float* __restrict__ u, const float* __restrict__ v,
                         float* __restrict__ Pj, float* __restrict__ Pi) {
  __shared__ u16 tile[64][65];
  int z = blockIdx.z;
  const float* inS = X + (size_t)z * NN * DI;
  int r0 = blockIdx.y * 64, c0 = blockIdx.x * 64;
  int t = threadIdx.x, cl = t & 15;
  f32x4 u4 = *(const f32x4*)(u + c0 + cl * 4);
  f32x4 v4 = *(const f32x4*)(v + c0 + cl * 4);
#pragma unroll
  for (int p = 0; p < 4; ++p) {
    int g = t + p * 256;
    int r = g >> 4, c4 = cl << 2;
    f32x4 x = *(const f32x4*)(inS + (size_t)(r0 + r) * DI + c0 + c4);
    u16x4v bv4;
    bv4[0] = f2b(x[0]); bv4[1] = f2b(x[1]); bv4[2] = f2b(x[2]); bv4[3] = f2b(x[3]);
    tile[r][c4+0] = bv4[0]; tile[r][c4+1] = bv4[1];
    tile[r][c4+2] = bv4[2]; tile[r][c4+3] = bv4[3];
    *(u16x4v*)(X123 + (size_t)z * NN * KCAT + (size_t)(r0 + r) * KCAT + c0 + c4) = bv4;
    float s1 = x[0]*u4[0] + x[1]*u4[1] + x[2]*u4[2] + x[3]*u4[3];
    float s2 = x[0]*v4[0] + x[1]*v4[1] + x[2]*v4[2] + x[3]*v4[3];
#pragma unroll
    for (int m = 1; m < 16; m <<= 1) {
      s1 += __shfl_xor(s1, m);
      s2 += __shfl_xor(s2, m);
    }
    if (cl == 0) {
      int gr = z * NN + r0 + r;
      Pj[(size_t)blockIdx.x * (NB * NN) + gr] = s1;
      Pi[(size_t)blockIdx.x * (NB * NN) + gr] = s2;
    }
  }
  __syncthreads();
#pragma unroll
  for (int p = 0; p < 4; ++p) {
    int g = t + p * 256;
    int oc = g >> 4, o4 = (g & 15) << 2;
    u16x4v wv;
    wv[0] = tile[o4+0][oc]; wv[1] = tile[o4+1][oc];
    wv[2] = tile[o4+2][oc]; wv[3] = tile[o4+3][oc];
    *(u16x4v*)(XbT + (size_t)z * DI * NN + (size_t)(c0 + oc) * NN + r0 + o4) = wv;
  }
}

// sj[r] = sum_cb Pj[cb][r]  (fixed order -> deterministic)
__global__ void sjsi_red(const float* __restrict__ Pj, const float* __restrict__ Pi,
                         float* __restrict__ sj, float* __restrict__ si) {
  int r = blockIdx.x * 256 + threadIdx.x;
  float s1 = 0.f, s2 = 0.f;
#pragma unroll
  for (int cb = 0; cb < 8; ++cb) {
    s1 += Pj[(size_t)cb * (NB * NN) + r];
    s2 += Pi[(size_t)cb * (NB * NN) + r];
  }
  sj[r] = s1; si[r] = s2;
}

// one wave per row: denom + transition (bf16), alpha kept in registers (32 VGPR).
__global__ void tmat_kernel(const float* __restrict__ Aa, const float* __restrict__ sj,
                            const float* __restrict__ si, const float* __restrict__ ccp,
                            u16* __restrict__ T, int rowbase) {
  int wid = threadIdx.x >> 6, lane = threadIdx.x & 63;
  int lr = blockIdx.x * 4 + wid;
  int gi = rowbase + lr;
  int b = gi >> 11;
  float siv = si[gi] + ccp[0];
  const f32x4* Arow = (const f32x4*)(Aa + (size_t)gi * NN);
  const f32x4* sjr = (const f32x4*)(sj + (size_t)b * NN);
  f32x4 al[8];
  float sum = 0.f;
#pragma unroll
  for (int t = 0; t < 8; ++t) {
    int f4 = lane + 64 * t;
    f32x4 a = Arow[f4];
    f32x4 s = sjr[f4];
#pragma unroll
    for (int j = 0; j < 4; ++j) {
      float e = s[j] + siv;
      e = e > 0.f ? e : 0.2f * e;
      al[t][j] = a[j] * __expf(e);
      sum += al[t][j];
    }
  }
#pragma unroll
  for (int o = 1; o < 64; o <<= 1) sum += __shfl_xor(sum, o);
  float rden = 1.0f / (sum + 1e-12f);
  u16* Trow = T + (size_t)lr * NN;
#pragma unroll
  for (int t = 0; t < 8; ++t) {
    int f4 = lane + 64 * t;
    u16x4v o4;
#pragma unroll
    for (int j = 0; j < 4; ++j) o4[j] = f2b(al[t][j] * rden);
    *(u16x4v*)(Trow + 4 * f4) = o4;
  }
}

// ---- GEMM: 128x64 tile, 4 waves, BK=64, 3-buffer counted-vmcnt(6) pipeline
// (round-6 HW-validated loop, VERBATIM). ----
struct GemmP {
  const u16 *A0, *A1, *A2;   // row-major M x Kc (per source)
  const u16 *B0, *B1, *B2;   // row-major N x Kc  (B transposed)
  const float* bias;
  void* out;
  u16* outT;                 // optional transposed bf16 output (ldOT = M-dim)
  int ldA, ldB, ldO, ldOT;
  size_t batchA, batchB, batchOut, batchOutT;
};

__device__ __forceinline__ void gload16(const u16* g, const u16* l) {
  __builtin_amdgcn_global_load_lds((const __attribute__((address_space(1))) void*)g,
                                   (__attribute__((address_space(3))) void*)l, 16, 0, 0);
}

// chunk-XOR swizzled LDS: global (row, c8) stored at LDS chunk row*8 + (c8 ^ (row&7)).
template <int NSRC, int KT, bool OBF, bool OTR>
__launch_bounds__(256)
__global__ void gemm_k(GemmP p) {
  __shared__ u16 As[3][128 * 64];
  __shared__ u16 Bs[3][64 * 64];
  int tid = threadIdx.x;
  int lane = tid & 63;
  int w = tid >> 6;
  int wr = w >> 1, wc = w & 1;
  int bm = blockIdx.x, bn = blockIdx.y, bz = blockIdx.z;
  const u16* Alist[3] = {p.A0, p.A1, p.A2};
  const u16* Blist[3] = {p.B0, p.B1, p.B2};
  int rof = lane & 15, ksel = lane >> 4, sw = lane & 7;
  int wub = (tid & 192) * 8;  // wave-uniform chunk base (elems) within a 256-chunk group
  f32x4 acc[4][2] = {};

  auto stage = [&](int t, int buf) {
    int s = t / KT;
    int k0 = (t - s * KT) * 64;
    const u16* Ag = Alist[s] + (size_t)bz * p.batchA + (size_t)bm * 128 * p.ldA;
    const u16* Bg = Blist[s] + (size_t)bz * p.batchB + (size_t)bn * 64 * p.ldB;
#pragma unroll
    for (int q = 0; q < 4; ++q) {
      int ch = q * 256 + tid;
      int row = ch >> 3;
      int c8 = (ch & 7) ^ (row & 7);
      gload16(Ag + (size_t)row * p.ldA + k0 + c8 * 8, &As[buf][0] + q * 2048 + wub);
    }
#pragma unroll
    for (int q = 0; q < 2; ++q) {
      int ch = q * 256 + tid;
      int row = ch >> 3;
      int c8 = (ch & 7) ^ (row & 7);
      gload16(Bg + (size_t)row * p.ldB + k0 + c8 * 8, &Bs[buf][0] + q * 2048 + wub);
    }
  };

  constexpr int TOT = NSRC * KT;
  stage(0, 0);
  stage(1, 1);
  asm volatile("s_waitcnt vmcnt(6)" ::: "memory");
  __builtin_amdgcn_s_barrier();
  __builtin_amdgcn_sched_barrier(0);

  int bufc = 0;
  for (int t = 0; t < TOT; ++t) {
    int nb = t + 2;
    if (nb < TOT) stage(nb, bufc == 0 ? 2 : bufc - 1);
    const u16* Asb = &As[bufc][0];
    const u16* Bsb = &Bs[bufc][0];
#pragma unroll
    for (int kk = 0; kk < 2; ++kk) {
      int csw = ((kk * 4 + ksel) ^ sw) * 8;
      s16x8 af[4], bfr[2];
#pragma unroll
      for (int mf = 0; mf < 4; ++mf) {
        int r = wr * 64 + mf * 16 + rof;
        af[mf] = *(const s16x8*)(Asb + r * 64 + csw);
      }
#pragma unroll
      for (int nf = 0; nf < 2; ++nf) {
        int r = wc * 32 + nf * 16 + rof;
        bfr[nf] = *(const s16x8*)(Bsb + r * 64 + csw);
      }
#pragma unroll
      for (int mf = 0; mf < 4; ++mf)
#pragma unroll
        for (int nf = 0; nf < 2; ++nf)
          acc[mf][nf] = __builtin_amdgcn_mfma_f32_16x16x32_bf16(af[mf], bfr[nf], acc[mf][nf], 0, 0, 0);
    }
    if (nb < TOT) {
      asm volatile("s_waitcnt vmcnt(6)" ::: "memory");   // stage(t+1) landed; t+2 in flight
    } else if (t + 1 < TOT) {
      asm volatile("s_waitcnt vmcnt(0)" ::: "memory");   // tail: drain last stage
    }
    if (t + 1 < TOT) {
      __builtin_amdgcn_s_barrier();
      __builtin_amdgcn_sched_barrier(0);
    }
    bufc = bufc + 1; if (bufc == 3) bufc = 0;
  }

  int rb = bm * 128 + wr * 64, cb = bn * 64 + wc * 32;
  int rsub = ksel << 2, csub = rof;
  if constexpr (OBF) {
    u16* o = (u16*)p.out + (size_t)bz * p.batchOut;
    u16* oT = OTR ? p.outT + (size_t)bz * p.batchOutT : nullptr;
#pragma unroll
    for (int mf = 0; mf < 4; ++mf)
#pragma unroll
      for (int nf = 0; nf < 2; ++nf) {
        int cidx = cb + nf * 16 + csub;
        u16x4v tv;
#pragma unroll
        for (int r = 0; r < 4; ++r) {
          tv[r] = f2b(acc[mf][nf][r]);
          o[(size_t)(rb + mf * 16 + rsub + r) * p.ldO + cidx] = tv[r];
        }
        if constexpr (OTR) {
          *(u16x4v*)(oT + (size_t)cidx * p.ldOT + rb + mf * 16 + rsub) = tv;
        }
      }
  } else {
    float* o = (float*)p.out + (size_t)bz * p.batchOut;
#pragma unroll
    for (int nf = 0; nf < 2; ++nf) {
      int cidx = cb + nf * 16 + csub;
      float bv_ = p.bias[cidx];
#pragma unroll
      for (int mf = 0; mf < 4; ++mf)
#pragma unroll
        for (int r = 0; r < 4; ++r) {
          float val = acc[mf][nf][r] + bv_;
          o[(size_t)(rb + mf * 16 + rsub + r) * p.ldO + cidx] = val > 0.f ? val : 0.f;
        }
    }
  }
}

// ---------------- launch ----------------
extern "C" void kernel_launch(void* const* d_in, const int* in_sizes, int n_in,
                              void* d_out, int out_size, void* d_ws, size_t ws_size,
                              hipStream_t stream) {
  const float* X  = (const float*)d_in[0];
  const float* A  = (const float*)d_in[1];
  const float* Wv = (const float*)d_in[2];
  const float* bv = (const float*)d_in[3];
  const float* aw = (const float*)d_in[4];
  const float* ab = (const float*)d_in[5];
  const float* Wk = (const float*)d_in[6];
  const float* bk = (const float*)d_in[7];
  float* out = (float*)d_out;

  char* ws = (char*)d_ws;
  size_t off = 0;
  auto alloc = [&](size_t bytes) -> void* {
    void* p = (void*)(ws + off);
    off = (off + bytes + 255) & ~(size_t)255;
    return p;
  };
  float* u    = (float*)alloc(DI * 4);
  float* v    = (float*)alloc(DI * 4);
  float* cc   = (float*)alloc(256);
  float* bsum = (float*)alloc(DOUTC * 4);
  float* sj   = (float*)alloc((size_t)NB * NN * 4);
  float* si   = (float*)alloc((size_t)NB * NN * 4);
  float* Pj   = (float*)alloc((size_t)8 * NB * NN * 4);
  float* Pi   = (float*)alloc((size_t)8 * NB * NN * 4);
  u16* BkT  = (u16*)alloc((size_t)DOUTC * KCAT * 2);           // [n][1536]
  u16* XbT  = (u16*)alloc((size_t)NB * DI * NN * 2);           // [b][512][2048]
  u16* X123 = (u16*)alloc((size_t)NB * NN * KCAT * 2);         // [b][2048][1536]
  u16* X1bT = (u16*)alloc((size_t)NB * DOUTC * NN * 2);        // [b][512][2048]
  size_t fixedEnd = off;
  int G = 4;
  while (G > 1 && fixedEnd + (size_t)G * NN * NN * 2 > ws_size) G >>= 1;
  u16* Tb = (u16*)alloc((size_t)G * NN * NN * 2);

  prep_all<<<3, 256, 0, stream>>>(Wv, aw, bk, bv, ab, u, v, bsum, cc);
  transWk_k<<<dim3(8, 8, 3), 256, 0, stream>>>(Wk, BkT);
  transX_k<<<dim3(8, 32, NB), 256, 0, stream>>>(X, XbT, X123, u, v, Pj, Pi);
  sjsi_red<<<NB * NN / 256, 256, 0, stream>>>(Pj, Pi, sj, si);

  for (int g0 = 0; g0 < NB; g0 += G) {
    tmat_kernel<<<G * NN / 4, 256, 0, stream>>>(A, sj, si, cc, Tb, g0 * NN);

    // X1 = T @ X  -> X123[:, 512:1024] (row-major) + X1bT (transposed)
    GemmP p1{};
    p1.A0 = p1.A1 = p1.A2 = Tb;
    p1.B0 = p1.B1 = p1.B2 = XbT + (size_t)g0 * DI * NN;
    p1.bias = nullptr;
    p1.out = X123 + (size_t)g0 * NN * KCAT + 512;
    p1.outT = X1bT + (size_t)g0 * DOUTC * NN;
    p1.ldA = NN; p1.ldB = NN; p1.ldO = KCAT; p1.ldOT = NN;
    p1.batchA = (size_t)NN * NN; p1.batchB = (size_t)DI * NN;
    p1.batchOut = (size_t)NN * KCAT; p1.batchOutT = (size_t)DOUTC * NN;
    gemm_k<1, 32, true, true><<<dim3(16, 8, G), 256, 0, stream>>>(p1);

    // X2 = T @ X1 -> X123[:, 1024:1536]
    GemmP p2 = p1;
    p2.B0 = p2.B1 = p2.B2 = X1bT + (size_t)g0 * DOUTC * NN;
    p2.out = X123 + (size_t)g0 * NN * KCAT + 1024;
    p2.outT = nullptr;
    gemm_k<1, 32, true, false><<<dim3(16, 8, G), 256, 0, stream>>>(p2);
  }

  // H = relu( X123 @ BkT^T + bsum )   (K = 1536 contiguous)
  GemmP p3{};
  p3.A0 = p3.A1 = p3.A2 = X123;
  p3.B0 = p3.B1 = p3.B2 = BkT;
  p3.bias = bsum; p3.out = out; p3.outT = nullptr;
  p3.ldA = KCAT; p3.ldB = KCAT; p3.ldO = DOUTC; p3.ldOT = 0;
  p3.batchA = 0; p3.batchB = 0; p3.batchOut = 0; p3.batchOutT = 0;
  gemm_k<1, 24, false, false><<<dim3(64, 8, 1), 256, 0, stream>>>(p3);
}

// Round 13
// 113.416 us; speedup vs baseline: 1.4297x; 1.1906x over previous
//
#include <hip/hip_runtime.h>

typedef float f32x4 __attribute__((ext_vector_type(4)));
typedef short s16x8 __attribute__((ext_vector_type(8)));
typedef unsigned short u16;
typedef unsigned char u8;
typedef u16 u16x4v __attribute__((ext_vector_type(4)));
typedef u16 u16x8v __attribute__((ext_vector_type(8)));

#define NB 4
#define NN 2048
#define DI 512
#define DOUTC 512
#define KP 3
#define KCAT 1536   // 3*512 concatenated K for gemm3

__device__ __forceinline__ u16 f2b(float f) {
  unsigned u = __builtin_bit_cast(unsigned, f);
  unsigned r = u + 0x7fffu + ((u >> 16) & 1u);
  return (u16)(r >> 16);
}
__device__ __forceinline__ float b2f(u16 h) {
  unsigned u = (unsigned)h << 16;
  return __builtin_bit_cast(float, u);
}
// pack 4 f32 -> 4 fp8 e4m3 (hardware cvt, RNE)
__device__ __forceinline__ unsigned pk4_fp8(float a, float b, float c, float d) {
  int r = __builtin_amdgcn_cvt_pk_fp8_f32(a, b, 0, false);
  r = __builtin_amdgcn_cvt_pk_fp8_f32(c, d, r, true);
  return (unsigned)r;
}

// ---------------- prep (merged): blocks 0-1 -> u,v,bsum ; block 2 -> cc ----
__global__ void prep_all(const float* __restrict__ Wv, const float* __restrict__ aw,
                         const float* __restrict__ bk, const float* __restrict__ bv,
                         const float* __restrict__ ab,
                         float* u, float* v, float* bsum, float* cc) {
  if (blockIdx.x < 2) {
    int c = blockIdx.x * 256 + threadIdx.x;
    float a1 = 0.f, a2 = 0.f;
    const float* row = Wv + (size_t)c * DOUTC;
    for (int d = 0; d < DOUTC; ++d) {
      float w = row[d];
      a1 += w * aw[d];
      a2 += w * aw[DOUTC + d];
    }
    u[c] = a1; v[c] = a2;
    bsum[c] = bk[c] + bk[DOUTC + c] + bk[2 * DOUTC + c];
  } else if (threadIdx.x < 64) {
    int l = threadIdx.x;
    float s = 0.f;
    for (int d = l; d < DOUTC; d += 64) s += bv[d] * (aw[d] + aw[DOUTC + d]);
    for (int o = 32; o; o >>= 1) s += __shfl_down(s, o);
    if (l == 0) cc[0] = s + ab[0];
  }
}

// Wk transpose -> BkT123 [n=512][1536] with k offset z*512.  grid (8,8,3)
__global__ void transWk_k(const float* __restrict__ in, u16* __restrict__ out) {
  __shared__ u16 tile[64][65];
  const float* inS = in + (size_t)blockIdx.z * DI * DOUTC;
  int r0 = blockIdx.y * 64, c0 = blockIdx.x * 64;
  int t = threadIdx.x;
#pragma unroll
  for (int p = 0; p < 4; ++p) {
    int g = t + p * 256;
    int r = g >> 4, c4 = (g & 15) << 2;
    f32x4 x = *(const f32x4*)(inS + (size_t)(r0 + r) * DOUTC + c0 + c4);
    tile[r][c4+0] = f2b(x[0]); tile[r][c4+1] = f2b(x[1]);
    tile[r][c4+2] = f2b(x[2]); tile[r][c4+3] = f2b(x[3]);
  }
  __syncthreads();
#pragma unroll
  for (int p = 0; p < 4; ++p) {
    int g = t + p * 256;
    int oc = g >> 4, o4 = (g & 15) << 2;
    u16x4v wv;
    wv[0] = tile[o4+0][oc]; wv[1] = tile[o4+1][oc];
    wv[2] = tile[o4+2][oc]; wv[3] = tile[o4+3][oc];
    *(u16x4v*)(out + (size_t)(c0 + oc) * KCAT + blockIdx.z * 512 + r0 + o4) = wv;
  }
}

// X transpose (fp8 XbT) + bf16 copy into X123 + fused sj/si partial dots.
// grid (8, 32, NB): c0 = bx*64 (X cols), r0 = by*64 (X rows), z = batch.
__global__ void transX_k(const float* __restrict__ X, u8* __restrict__ XbT,
                         u16* __restrict__ X123,
                         const float* __restrict__ u, const float* __restrict__ v,
                         float* __restrict__ Pj, float* __restrict__ Pi) {
  __shared__ u16 tile[64][65];
  int z = blockIdx.z;
  const float* inS = X + (size_t)z * NN * DI;
  int r0 = blockIdx.y * 64, c0 = blockIdx.x * 64;
  int t = threadIdx.x, cl = t & 15;
  f32x4 u4 = *(const f32x4*)(u + c0 + cl * 4);
  f32x4 v4 = *(const f32x4*)(v + c0 + cl * 4);
#pragma unroll
  for (int p = 0; p < 4; ++p) {
    int g = t + p * 256;
    int r = g >> 4, c4 = cl << 2;
    f32x4 x = *(const f32x4*)(inS + (size_t)(r0 + r) * DI + c0 + c4);
    u16x4v bv4;
    bv4[0] = f2b(x[0]); bv4[1] = f2b(x[1]); bv4[2] = f2b(x[2]); bv4[3] = f2b(x[3]);
    tile[r][c4+0] = bv4[0]; tile[r][c4+1] = bv4[1];
    tile[r][c4+2] = bv4[2]; tile[r][c4+3] = bv4[3];
    *(u16x4v*)(X123 + (size_t)z * NN * KCAT + (size_t)(r0 + r) * KCAT + c0 + c4) = bv4;
    float s1 = x[0]*u4[0] + x[1]*u4[1] + x[2]*u4[2] + x[3]*u4[3];
    float s2 = x[0]*v4[0] + x[1]*v4[1] + x[2]*v4[2] + x[3]*v4[3];
#pragma unroll
    for (int m = 1; m < 16; m <<= 1) {
      s1 += __shfl_xor(s1, m);
      s2 += __shfl_xor(s2, m);
    }
    if (cl == 0) {
      int gr = z * NN + r0 + r;
      Pj[(size_t)blockIdx.x * (NB * NN) + gr] = s1;
      Pi[(size_t)blockIdx.x * (NB * NN) + gr] = s2;
    }
  }
  __syncthreads();
#pragma unroll
  for (int p = 0; p < 4; ++p) {
    int g = t + p * 256;
    int oc = g >> 4, o4 = (g & 15) << 2;
    unsigned w4 = pk4_fp8(b2f(tile[o4+0][oc]), b2f(tile[o4+1][oc]),
                          b2f(tile[o4+2][oc]), b2f(tile[o4+3][oc]));
    *(unsigned*)(XbT + (size_t)z * DI * NN + (size_t)(c0 + oc) * NN + r0 + o4) = w4;
  }
}

// sj[r] = sum_cb Pj[cb][r]  (fixed order -> deterministic)
__global__ void sjsi_red(const float* __restrict__ Pj, const float* __restrict__ Pi,
                         float* __restrict__ sj, float* __restrict__ si) {
  int r = blockIdx.x * 256 + threadIdx.x;
  float s1 = 0.f, s2 = 0.f;
#pragma unroll
  for (int cb = 0; cb < 8; ++cb) {
    s1 += Pj[(size_t)cb * (NB * NN) + r];
    s2 += Pi[(size_t)cb * (NB * NN) + r];
  }
  sj[r] = s1; si[r] = s2;
}

// one wave per row: denom + transition. T stored as fp8 e4m3 scaled x256.
__global__ void tmat_kernel(const float* __restrict__ Aa, const float* __restrict__ sj,
                            const float* __restrict__ si, const float* __restrict__ ccp,
                            u8* __restrict__ T, int rowbase) {
  int wid = threadIdx.x >> 6, lane = threadIdx.x & 63;
  int lr = blockIdx.x * 4 + wid;
  int gi = rowbase + lr;
  int b = gi >> 11;
  float siv = si[gi] + ccp[0];
  const f32x4* Arow = (const f32x4*)(Aa + (size_t)gi * NN);
  const f32x4* sjr = (const f32x4*)(sj + (size_t)b * NN);
  f32x4 al[8];
  float sum = 0.f;
#pragma unroll
  for (int t = 0; t < 8; ++t) {
    int f4 = lane + 64 * t;
    f32x4 a = Arow[f4];
    f32x4 s = sjr[f4];
#pragma unroll
    for (int j = 0; j < 4; ++j) {
      float e = s[j] + siv;
      e = e > 0.f ? e : 0.2f * e;
      al[t][j] = a[j] * __expf(e);
      sum += al[t][j];
    }
  }
#pragma unroll
  for (int o = 1; o < 64; o <<= 1) sum += __shfl_xor(sum, o);
  float rs = 256.0f / (sum + 1e-12f);   // fp8 scale x256 folded into 1/den
  u8* Trow = T + (size_t)lr * NN;
#pragma unroll
  for (int t = 0; t < 8; ++t) {
    int f4 = lane + 64 * t;
    unsigned w4 = pk4_fp8(al[t][0] * rs, al[t][1] * rs, al[t][2] * rs, al[t][3] * rs);
    *(unsigned*)(Trow + 4 * f4) = w4;
  }
}

__device__ __forceinline__ void gload16(const void* g, const void* l) {
  __builtin_amdgcn_global_load_lds((const __attribute__((address_space(1))) void*)g,
                                   (__attribute__((address_space(3))) void*)l, 16, 0, 0);
}

// ---- fp8 GEMM: 128x64 tile, 4 waves, BK=128, 3-buffer counted-vmcnt(6)
// pipeline. Same sync skeleton / stage geometry / chunk-XOR as the R6-proven
// bf16 loop (6x16B loads per stage, 8 chunks/row); half the barriers (TOT=16).
struct Gemm8P {
  const u8 *Ab;              // M x K fp8, ldA = K bytes
  const u8 *Bb;              // N x K fp8
  u16* out;                  // bf16 row-major, ldO in elems
  u8* outT;                  // optional fp8 transposed output (x oscT)
  int ldA, ldB, ldO, ldOT;
  size_t batchA, batchB, batchOut, batchOutT;
  float osc, oscT;
};

template <int KT, bool OTR>
__launch_bounds__(256)
__global__ void gemm8_k(Gemm8P p) {
  __shared__ u8 As[3][128 * 128];
  __shared__ u8 Bs[3][64 * 128];
  int tid = threadIdx.x;
  int lane = tid & 63;
  int w = tid >> 6;
  int wr = w >> 1, wc = w & 1;
  int bm = blockIdx.x, bn = blockIdx.y, bz = blockIdx.z;
  int rof = lane & 15, ksel = lane >> 4, sw = lane & 7;
  int wub = (tid & 192) * 16;  // byte base: wave-uniform chunk group
  f32x4 acc[4][2] = {};
  const u8* Ag = p.Ab + (size_t)bz * p.batchA + (size_t)bm * 128 * p.ldA;
  const u8* Bg = p.Bb + (size_t)bz * p.batchB + (size_t)bn * 64 * p.ldB;

  auto stage = [&](int t, int buf) {
    int k0 = t * 128;
#pragma unroll
    for (int q = 0; q < 4; ++q) {
      int ch = q * 256 + tid;
      int row = ch >> 3;
      int c8 = (ch & 7) ^ (row & 7);
      gload16(Ag + (size_t)row * p.ldA + k0 + c8 * 16, &As[buf][0] + q * 4096 + wub);
    }
#pragma unroll
    for (int q = 0; q < 2; ++q) {
      int ch = q * 256 + tid;
      int row = ch >> 3;
      int c8 = (ch & 7) ^ (row & 7);
      gload16(Bg + (size_t)row * p.ldB + k0 + c8 * 16, &Bs[buf][0] + q * 4096 + wub);
    }
  };

  constexpr int TOT = KT;
  stage(0, 0);
  stage(1, 1);
  asm volatile("s_waitcnt vmcnt(6)" ::: "memory");
  __builtin_amdgcn_s_barrier();
  __builtin_amdgcn_sched_barrier(0);

  int bufc = 0;
  for (int t = 0; t < TOT; ++t) {
    int nb = t + 2;
    if (nb < TOT) stage(nb, bufc == 0 ? 2 : bufc - 1);
    const u8* Asb = &As[bufc][0];
    const u8* Bsb = &Bs[bufc][0];
#pragma unroll
    for (int kk = 0; kk < 4; ++kk) {
      int csw = ((2 * kk + (ksel >> 1)) ^ sw) * 16 + (ksel & 1) * 8;
      long af[4], bfr[2];
#pragma unroll
      for (int mf = 0; mf < 4; ++mf) {
        int r = wr * 64 + mf * 16 + rof;
        af[mf] = *(const long*)(Asb + (size_t)r * 128 + csw);
      }
#pragma unroll
      for (int nf = 0; nf < 2; ++nf) {
        int r = wc * 32 + nf * 16 + rof;
        bfr[nf] = *(const long*)(Bsb + (size_t)r * 128 + csw);
      }
#pragma unroll
      for (int mf = 0; mf < 4; ++mf)
#pragma unroll
        for (int nf = 0; nf < 2; ++nf)
          acc[mf][nf] = __builtin_amdgcn_mfma_f32_16x16x32_fp8_fp8(af[mf], bfr[nf], acc[mf][nf], 0, 0, 0);
    }
    if (nb < TOT) {
      asm volatile("s_waitcnt vmcnt(6)" ::: "memory");   // stage(t+1) landed; t+2 in flight
    } else if (t + 1 < TOT) {
      asm volatile("s_waitcnt vmcnt(0)" ::: "memory");   // tail: drain last stage
    }
    if (t + 1 < TOT) {
      __builtin_amdgcn_s_barrier();
      __builtin_amdgcn_sched_barrier(0);
    }
    bufc = bufc + 1; if (bufc == 3) bufc = 0;
  }

  int rb = bm * 128 + wr * 64, cb = bn * 64 + wc * 32;
  int rsub = ksel << 2, csub = rof;
  u16* o = p.out + (size_t)bz * p.batchOut;
  u8* oT = OTR ? p.outT + (size_t)bz * p.batchOutT : nullptr;
#pragma unroll
  for (int mf = 0; mf < 4; ++mf)
#pragma unroll
    for (int nf = 0; nf < 2; ++nf) {
      int cidx = cb + nf * 16 + csub;
      f32x4 av = acc[mf][nf];
#pragma unroll
      for (int r = 0; r < 4; ++r)
        o[(size_t)(rb + mf * 16 + rsub + r) * p.ldO + cidx] = f2b(av[r] * p.osc);
      if constexpr (OTR) {
        unsigned w4 = pk4_fp8(av[0] * p.oscT, av[1] * p.oscT,
                              av[2] * p.oscT, av[3] * p.oscT);
        *(unsigned*)(oT + (size_t)cidx * p.ldOT + rb + mf * 16 + rsub) = w4;
      }
    }
}

// ---- bf16 GEMM (gemm3 only): R6/R12-proven loop, verbatim ----
struct GemmP {
  const u16 *A0, *A1, *A2;
  const u16 *B0, *B1, *B2;
  const float* bias;
  void* out;
  u16* outT;
  int ldA, ldB, ldO, ldOT;
  size_t batchA, batchB, batchOut, batchOutT;
};

template <int NSRC, int KT, bool OBF, bool OTR>
__launch_bounds__(256)
__global__ void gemm_k(GemmP p) {
  __shared__ u16 As[3][128 * 64];
  __shared__ u16 Bs[3][64 * 64];
  int tid = threadIdx.x;
  int lane = tid & 63;
  int w = tid >> 6;
  int wr = w >> 1, wc = w & 1;
  int bm = blockIdx.x, bn = blockIdx.y, bz = blockIdx.z;
  const u16* Alist[3] = {p.A0, p.A1, p.A2};
  const u16* Blist[3] = {p.B0, p.B1, p.B2};
  int rof = lane & 15, ksel = lane >> 4, sw = lane & 7;
  int wub = (tid & 192) * 8;
  f32x4 acc[4][2] = {};

  auto stage = [&](int t, int buf) {
    int s = t / KT;
    int k0 = (t - s * KT) * 64;
    const u16* Ag = Alist[s] + (size_t)bz * p.batchA + (size_t)bm * 128 * p.ldA;
    const u16* Bg = Blist[s] + (size_t)bz * p.batchB + (size_t)bn * 64 * p.ldB;
#pragma unroll
    for (int q = 0; q < 4; ++q) {
      int ch = q * 256 + tid;
      int row = ch >> 3;
      int c8 = (ch & 7) ^ (row & 7);
      gload16(Ag + (size_t)row * p.ldA + k0 + c8 * 8, &As[buf][0] + q * 2048 + wub);
    }
#pragma unroll
    for (int q = 0; q < 2; ++q) {
      int ch = q * 256 + tid;
      int row = ch >> 3;
      int c8 = (ch & 7) ^ (row & 7);
      gload16(Bg + (size_t)row * p.ldB + k0 + c8 * 8, &Bs[buf][0] + q * 2048 + wub);
    }
  };

  constexpr int TOT = NSRC * KT;
  stage(0, 0);
  stage(1, 1);
  asm volatile("s_waitcnt vmcnt(6)" ::: "memory");
  __builtin_amdgcn_s_barrier();
  __builtin_amdgcn_sched_barrier(0);

  int bufc = 0;
  for (int t = 0; t < TOT; ++t) {
    int nb = t + 2;
    if (nb < TOT) stage(nb, bufc == 0 ? 2 : bufc - 1);
    const u16* Asb = &As[bufc][0];
    const u16* Bsb = &Bs[bufc][0];
#pragma unroll
    for (int kk = 0; kk < 2; ++kk) {
      int csw = ((kk * 4 + ksel) ^ sw) * 8;
      s16x8 af[4], bfr[2];
#pragma unroll
      for (int mf = 0; mf < 4; ++mf) {
        int r = wr * 64 + mf * 16 + rof;
        af[mf] = *(const s16x8*)(Asb + r * 64 + csw);
      }
#pragma unroll
      for (int nf = 0; nf < 2; ++nf) {
        int r = wc * 32 + nf * 16 + rof;
        bfr[nf] = *(const s16x8*)(Bsb + r * 64 + csw);
      }
#pragma unroll
      for (int mf = 0; mf < 4; ++mf)
#pragma unroll
        for (int nf = 0; nf < 2; ++nf)
          acc[mf][nf] = __builtin_amdgcn_mfma_f32_16x16x32_bf16(af[mf], bfr[nf], acc[mf][nf], 0, 0, 0);
    }
    if (nb < TOT) {
      asm volatile("s_waitcnt vmcnt(6)" ::: "memory");
    } else if (t + 1 < TOT) {
      asm volatile("s_waitcnt vmcnt(0)" ::: "memory");
    }
    if (t + 1 < TOT) {
      __builtin_amdgcn_s_barrier();
      __builtin_amdgcn_sched_barrier(0);
    }
    bufc = bufc + 1; if (bufc == 3) bufc = 0;
  }

  int rb = bm * 128 + wr * 64, cb = bn * 64 + wc * 32;
  int rsub = ksel << 2, csub = rof;
  if constexpr (OBF) {
    u16* o = (u16*)p.out + (size_t)bz * p.batchOut;
    u16* oT = OTR ? p.outT + (size_t)bz * p.batchOutT : nullptr;
#pragma unroll
    for (int mf = 0; mf < 4; ++mf)
#pragma unroll
      for (int nf = 0; nf < 2; ++nf) {
        int cidx = cb + nf * 16 + csub;
        u16x4v tv;
#pragma unroll
        for (int r = 0; r < 4; ++r) {
          tv[r] = f2b(acc[mf][nf][r]);
          o[(size_t)(rb + mf * 16 + rsub + r) * p.ldO + cidx] = tv[r];
        }
        if constexpr (OTR) {
          *(u16x4v*)(oT + (size_t)cidx * p.ldOT + rb + mf * 16 + rsub) = tv;
        }
      }
  } else {
    float* o = (float*)p.out + (size_t)bz * p.batchOut;
#pragma unroll
    for (int nf = 0; nf < 2; ++nf) {
      int cidx = cb + nf * 16 + csub;
      float bv_ = p.bias[cidx];
#pragma unroll
      for (int mf = 0; mf < 4; ++mf)
#pragma unroll
        for (int r = 0; r < 4; ++r) {
          float val = acc[mf][nf][r] + bv_;
          o[(size_t)(rb + mf * 16 + rsub + r) * p.ldO + cidx] = val > 0.f ? val : 0.f;
        }
    }
  }
}

// ---------------- launch ----------------
extern "C" void kernel_launch(void* const* d_in, const int* in_sizes, int n_in,
                              void* d_out, int out_size, void* d_ws, size_t ws_size,
                              hipStream_t stream) {
  const float* X  = (const float*)d_in[0];
  const float* A  = (const float*)d_in[1];
  const float* Wv = (const float*)d_in[2];
  const float* bv = (const float*)d_in[3];
  const float* aw = (const float*)d_in[4];
  const float* ab = (const float*)d_in[5];
  const float* Wk = (const float*)d_in[6];
  const float* bk = (const float*)d_in[7];
  float* out = (float*)d_out;

  char* ws = (char*)d_ws;
  size_t off = 0;
  auto alloc = [&](size_t bytes) -> void* {
    void* p = (void*)(ws + off);
    off = (off + bytes + 255) & ~(size_t)255;
    return p;
  };
  float* u    = (float*)alloc(DI * 4);
  float* v    = (float*)alloc(DI * 4);
  float* cc   = (float*)alloc(256);
  float* bsum = (float*)alloc(DOUTC * 4);
  float* sj   = (float*)alloc((size_t)NB * NN * 4);
  float* si   = (float*)alloc((size_t)NB * NN * 4);
  float* Pj   = (float*)alloc((size_t)8 * NB * NN * 4);
  float* Pi   = (float*)alloc((size_t)8 * NB * NN * 4);
  u16* BkT  = (u16*)alloc((size_t)DOUTC * KCAT * 2);           // [n][1536] bf16
  u8*  XbT8 = (u8*)alloc((size_t)NB * DI * NN);                // [b][512][2048] fp8
  u16* X123 = (u16*)alloc((size_t)NB * NN * KCAT * 2);         // [b][2048][1536] bf16
  u8*  X1bT8= (u8*)alloc((size_t)NB * DOUTC * NN);             // [b][512][2048] fp8 (x16)
  size_t fixedEnd = off;
  int G = 4;
  while (G > 1 && fixedEnd + (size_t)G * NN * NN > ws_size) G >>= 1;
  u8* Tb8 = (u8*)alloc((size_t)G * NN * NN);                   // fp8 T (x256)

  prep_all<<<3, 256, 0, stream>>>(Wv, aw, bk, bv, ab, u, v, bsum, cc);
  transWk_k<<<dim3(8, 8, 3), 256, 0, stream>>>(Wk, BkT);
  transX_k<<<dim3(8, 32, NB), 256, 0, stream>>>(X, XbT8, X123, u, v, Pj, Pi);
  sjsi_red<<<NB * NN / 256, 256, 0, stream>>>(Pj, Pi, sj, si);

  for (int g0 = 0; g0 < NB; g0 += G) {
    tmat_kernel<<<G * NN / 4, 256, 0, stream>>>(A, sj, si, cc, Tb8, g0 * NN);

    // X1 = T @ X : A = 256*T (fp8), B = X^T (fp8); out bf16 = acc/256 into
    // X123[:, 512:1024]; outT fp8 = acc*(16/256) = 16*X1 for gemm2's B.
    Gemm8P p1{};
    p1.Ab = Tb8;
    p1.Bb = XbT8 + (size_t)g0 * DI * NN;
    p1.out = X123 + (size_t)g0 * NN * KCAT + 512;
    p1.outT = X1bT8 + (size_t)g0 * DOUTC * NN;
    p1.ldA = NN; p1.ldB = NN; p1.ldO = KCAT; p1.ldOT = NN;
    p1.batchA = (size_t)NN * NN; p1.batchB = (size_t)DI * NN;
    p1.batchOut = (size_t)NN * KCAT; p1.batchOutT = (size_t)DOUTC * NN;
    p1.osc = 1.0f / 256.0f; p1.oscT = 16.0f / 256.0f;
    gemm8_k<16, true><<<dim3(16, 8, G), 256, 0, stream>>>(p1);

    // X2 = T @ X1 : A = 256*T, B = 16*X1^T; out bf16 = acc/4096 into
    // X123[:, 1024:1536].
    Gemm8P p2 = p1;
    p2.Bb = X1bT8 + (size_t)g0 * DOUTC * NN;
    p2.out = X123 + (size_t)g0 * NN * KCAT + 1024;
    p2.outT = nullptr;
    p2.osc = 1.0f / 4096.0f;
    gemm8_k<16, false><<<dim3(16, 8, G), 256, 0, stream>>>(p2);
  }

  // H = relu( X123 @ BkT^T + bsum )   (bf16, K = 1536 contiguous)
  GemmP p3{};
  p3.A0 = p3.A1 = p3.A2 = X123;
  p3.B0 = p3.B1 = p3.B2 = BkT;
  p3.bias = bsum; p3.out = out; p3.outT = nullptr;
  p3.ldA = KCAT; p3.ldB = KCAT; p3.ldO = DOUTC; p3.ldOT = 0;
  p3.batchA = 0; p3.batchB = 0; p3.batchOut = 0; p3.batchOutT = 0;
  gemm_k<1, 24, false, false><<<dim3(64, 8, 1), 256, 0, stream>>>(p3);
}

// Round 14
// 109.358 us; speedup vs baseline: 1.4828x; 1.0371x over previous
//
#include <hip/hip_runtime.h>

typedef float f32x4 __attribute__((ext_vector_type(4)));
typedef short s16x8 __attribute__((ext_vector_type(8)));
typedef unsigned short u16;
typedef unsigned char u8;
typedef u16 u16x4v __attribute__((ext_vector_type(4)));
typedef u16 u16x8v __attribute__((ext_vector_type(8)));

#define NB 4
#define NN 2048
#define DI 512
#define DOUTC 512
#define KP 3
#define ROWB 2048   // bytes per concatenated A/B row: 512 bf16 | 512 fp8 | 512 fp8

__device__ __forceinline__ u16 f2b(float f) {
  unsigned u = __builtin_bit_cast(unsigned, f);
  unsigned r = u + 0x7fffu + ((u >> 16) & 1u);
  return (u16)(r >> 16);
}
__device__ __forceinline__ float b2f(u16 h) {
  unsigned u = (unsigned)h << 16;
  return __builtin_bit_cast(float, u);
}
// pack 4 f32 -> 4 fp8 e4m3 (hardware cvt, RNE)
__device__ __forceinline__ unsigned pk4_fp8(float a, float b, float c, float d) {
  int r = __builtin_amdgcn_cvt_pk_fp8_f32(a, b, 0, false);
  r = __builtin_amdgcn_cvt_pk_fp8_f32(c, d, r, true);
  return (unsigned)r;
}

// ---------------- prep (merged): blocks 0-1 -> u,v,bsum ; block 2 -> cc ----
__global__ void prep_all(const float* __restrict__ Wv, const float* __restrict__ aw,
                         const float* __restrict__ bk, const float* __restrict__ bv,
                         const float* __restrict__ ab,
                         float* u, float* v, float* bsum, float* cc) {
  if (blockIdx.x < 2) {
    int c = blockIdx.x * 256 + threadIdx.x;
    float a1 = 0.f, a2 = 0.f;
    const float* row = Wv + (size_t)c * DOUTC;
    for (int d = 0; d < DOUTC; ++d) {
      float w = row[d];
      a1 += w * aw[d];
      a2 += w * aw[DOUTC + d];
    }
    u[c] = a1; v[c] = a2;
    bsum[c] = bk[c] + bk[DOUTC + c] + bk[2 * DOUTC + c];
  } else if (threadIdx.x < 64) {
    int l = threadIdx.x;
    float s = 0.f;
    for (int d = l; d < DOUTC; d += 64) s += bv[d] * (aw[d] + aw[DOUTC + d]);
    for (int o = 32; o; o >>= 1) s += __shfl_down(s, o);
    if (l == 0) cc[0] = s + ab[0];
  }
}

// Wk transpose into BkTB [n=512][ROWB]: z=0 -> bf16 W0^T (bytes 0..1023);
// z=1,2 -> fp8 x64 W{1,2}^T (bytes 1024+/1536+).  grid (8,8,3)
__global__ void transWk_k(const float* __restrict__ in, u8* __restrict__ out) {
  __shared__ u16 tile[64][65];
  int z = blockIdx.z;
  const float* inS = in + (size_t)z * DI * DOUTC;
  int r0 = blockIdx.y * 64, c0 = blockIdx.x * 64;
  int t = threadIdx.x;
#pragma unroll
  for (int p = 0; p < 4; ++p) {
    int g = t + p * 256;
    int r = g >> 4, c4 = (g & 15) << 2;
    f32x4 x = *(const f32x4*)(inS + (size_t)(r0 + r) * DOUTC + c0 + c4);
    tile[r][c4+0] = f2b(x[0]); tile[r][c4+1] = f2b(x[1]);
    tile[r][c4+2] = f2b(x[2]); tile[r][c4+3] = f2b(x[3]);
  }
  __syncthreads();
#pragma unroll
  for (int p = 0; p < 4; ++p) {
    int g = t + p * 256;
    int oc = g >> 4, o4 = (g & 15) << 2;
    if (z == 0) {
      u16x4v wv;
      wv[0] = tile[o4+0][oc]; wv[1] = tile[o4+1][oc];
      wv[2] = tile[o4+2][oc]; wv[3] = tile[o4+3][oc];
      *(u16x4v*)(out + (size_t)(c0 + oc) * ROWB + (size_t)(r0 + o4) * 2) = wv;
    } else {
      unsigned w4 = pk4_fp8(b2f(tile[o4+0][oc]) * 64.f, b2f(tile[o4+1][oc]) * 64.f,
                            b2f(tile[o4+2][oc]) * 64.f, b2f(tile[o4+3][oc]) * 64.f);
      *(unsigned*)(out + (size_t)(c0 + oc) * ROWB + 1024 + (z - 1) * 512 + r0 + o4) = w4;
    }
  }
}

// X transpose (fp8 XbT) + bf16 copy into X123B bytes 0..1023 + fused sj/si dots.
// grid (8, 32, NB)
__global__ void transX_k(const float* __restrict__ X, u8* __restrict__ XbT,
                         u8* __restrict__ X123B,
                         const float* __restrict__ u, const float* __restrict__ v,
                         float* __restrict__ Pj, float* __restrict__ Pi) {
  __shared__ u16 tile[64][65];
  int z = blockIdx.z;
  const float* inS = X + (size_t)z * NN * DI;
  int r0 = blockIdx.y * 64, c0 = blockIdx.x * 64;
  int t = threadIdx.x, cl = t & 15;
  f32x4 u4 = *(const f32x4*)(u + c0 + cl * 4);
  f32x4 v4 = *(const f32x4*)(v + c0 + cl * 4);
#pragma unroll
  for (int p = 0; p < 4; ++p) {
    int g = t + p * 256;
    int r = g >> 4, c4 = cl << 2;
    f32x4 x = *(const f32x4*)(inS + (size_t)(r0 + r) * DI + c0 + c4);
    u16x4v bv4;
    bv4[0] = f2b(x[0]); bv4[1] = f2b(x[1]); bv4[2] = f2b(x[2]); bv4[3] = f2b(x[3]);
    tile[r][c4+0] = bv4[0]; tile[r][c4+1] = bv4[1];
    tile[r][c4+2] = bv4[2]; tile[r][c4+3] = bv4[3];
    *(u16x4v*)(X123B + (size_t)z * NN * ROWB + (size_t)(r0 + r) * ROWB +
               (size_t)(c0 + c4) * 2) = bv4;
    float s1 = x[0]*u4[0] + x[1]*u4[1] + x[2]*u4[2] + x[3]*u4[3];
    float s2 = x[0]*v4[0] + x[1]*v4[1] + x[2]*v4[2] + x[3]*v4[3];
#pragma unroll
    for (int m = 1; m < 16; m <<= 1) {
      s1 += __shfl_xor(s1, m);
      s2 += __shfl_xor(s2, m);
    }
    if (cl == 0) {
      int gr = z * NN + r0 + r;
      Pj[(size_t)blockIdx.x * (NB * NN) + gr] = s1;
      Pi[(size_t)blockIdx.x * (NB * NN) + gr] = s2;
    }
  }
  __syncthreads();
#pragma unroll
  for (int p = 0; p < 4; ++p) {
    int g = t + p * 256;
    int oc = g >> 4, o4 = (g & 15) << 2;
    unsigned w4 = pk4_fp8(b2f(tile[o4+0][oc]), b2f(tile[o4+1][oc]),
                          b2f(tile[o4+2][oc]), b2f(tile[o4+3][oc]));
    *(unsigned*)(XbT + (size_t)z * DI * NN + (size_t)(c0 + oc) * NN + r0 + o4) = w4;
  }
}

// sj[r] = sum_cb Pj[cb][r]  (fixed order -> deterministic)
__global__ void sjsi_red(const float* __restrict__ Pj, const float* __restrict__ Pi,
                         float* __restrict__ sj, float* __restrict__ si) {
  int r = blockIdx.x * 256 + threadIdx.x;
  float s1 = 0.f, s2 = 0.f;
#pragma unroll
  for (int cb = 0; cb < 8; ++cb) {
    s1 += Pj[(size_t)cb * (NB * NN) + r];
    s2 += Pi[(size_t)cb * (NB * NN) + r];
  }
  sj[r] = s1; si[r] = s2;
}

// one wave per row: denom + transition. T stored as fp8 e4m3 scaled x256.
__global__ void tmat_kernel(const float* __restrict__ Aa, const float* __restrict__ sj,
                            const float* __restrict__ si, const float* __restrict__ ccp,
                            u8* __restrict__ T, int rowbase) {
  int wid = threadIdx.x >> 6, lane = threadIdx.x & 63;
  int lr = blockIdx.x * 4 + wid;
  int gi = rowbase + lr;
  int b = gi >> 11;
  float siv = si[gi] + ccp[0];
  const f32x4* Arow = (const f32x4*)(Aa + (size_t)gi * NN);
  const f32x4* sjr = (const f32x4*)(sj + (size_t)b * NN);
  f32x4 al[8];
  float sum = 0.f;
#pragma unroll
  for (int t = 0; t < 8; ++t) {
    int f4 = lane + 64 * t;
    f32x4 a = Arow[f4];
    f32x4 s = sjr[f4];
#pragma unroll
    for (int j = 0; j < 4; ++j) {
      float e = s[j] + siv;
      e = e > 0.f ? e : 0.2f * e;
      al[t][j] = a[j] * __expf(e);
      sum += al[t][j];
    }
  }
#pragma unroll
  for (int o = 1; o < 64; o <<= 1) sum += __shfl_xor(sum, o);
  float rs = 256.0f / (sum + 1e-12f);
  u8* Trow = T + (size_t)lr * NN;
#pragma unroll
  for (int t = 0; t < 8; ++t) {
    int f4 = lane + 64 * t;
    unsigned w4 = pk4_fp8(al[t][0] * rs, al[t][1] * rs, al[t][2] * rs, al[t][3] * rs);
    *(unsigned*)(Trow + 4 * f4) = w4;
  }
}

__device__ __forceinline__ void gload16(const void* g, const void* l) {
  __builtin_amdgcn_global_load_lds((const __attribute__((address_space(1))) void*)g,
                                   (__attribute__((address_space(3))) void*)l, 16, 0, 0);
}

// ---- fp8 T-GEMM (R13 HW-validated loop). Epilogue: row-major fp8 (x oscR)
// and optional transposed fp8 (same scale). ----
struct Gemm8P {
  const u8 *Ab;              // M x K fp8, ldA bytes
  const u8 *Bb;              // N x K fp8, ldB bytes
  u8* outR;                  // row-major fp8 out, ldOB bytes
  u8* outT;                  // optional transposed fp8 out, ldOT bytes
  int ldA, ldB, ldOB, ldOT;
  size_t batchA, batchB, batchOutB, batchOutT;
  float oscR;
};

template <int KT, bool OTR>
__launch_bounds__(256)
__global__ void gemm8_k(Gemm8P p) {
  __shared__ u8 As[3][128 * 128];
  __shared__ u8 Bs[3][64 * 128];
  int tid = threadIdx.x;
  int lane = tid & 63;
  int w = tid >> 6;
  int wr = w >> 1, wc = w & 1;
  int bm = blockIdx.x, bn = blockIdx.y, bz = blockIdx.z;
  int rof = lane & 15, ksel = lane >> 4, sw = lane & 7;
  int wub = (tid & 192) * 16;
  f32x4 acc[4][2] = {};
  const u8* Ag = p.Ab + (size_t)bz * p.batchA + (size_t)bm * 128 * p.ldA;
  const u8* Bg = p.Bb + (size_t)bz * p.batchB + (size_t)bn * 64 * p.ldB;

  auto stage = [&](int t, int buf) {
    int k0 = t * 128;
#pragma unroll
    for (int q = 0; q < 4; ++q) {
      int ch = q * 256 + tid;
      int row = ch >> 3;
      int c8 = (ch & 7) ^ (row & 7);
      gload16(Ag + (size_t)row * p.ldA + k0 + c8 * 16, &As[buf][0] + q * 4096 + wub);
    }
#pragma unroll
    for (int q = 0; q < 2; ++q) {
      int ch = q * 256 + tid;
      int row = ch >> 3;
      int c8 = (ch & 7) ^ (row & 7);
      gload16(Bg + (size_t)row * p.ldB + k0 + c8 * 16, &Bs[buf][0] + q * 4096 + wub);
    }
  };

  constexpr int TOT = KT;
  stage(0, 0);
  stage(1, 1);
  asm volatile("s_waitcnt vmcnt(6)" ::: "memory");
  __builtin_amdgcn_s_barrier();
  __builtin_amdgcn_sched_barrier(0);

  int bufc = 0;
  for (int t = 0; t < TOT; ++t) {
    int nb = t + 2;
    if (nb < TOT) stage(nb, bufc == 0 ? 2 : bufc - 1);
    const u8* Asb = &As[bufc][0];
    const u8* Bsb = &Bs[bufc][0];
#pragma unroll
    for (int kk = 0; kk < 4; ++kk) {
      int csw = ((2 * kk + (ksel >> 1)) ^ sw) * 16 + (ksel & 1) * 8;
      long af[4], bfr[2];
#pragma unroll
      for (int mf = 0; mf < 4; ++mf) {
        int r = wr * 64 + mf * 16 + rof;
        af[mf] = *(const long*)(Asb + (size_t)r * 128 + csw);
      }
#pragma unroll
      for (int nf = 0; nf < 2; ++nf) {
        int r = wc * 32 + nf * 16 + rof;
        bfr[nf] = *(const long*)(Bsb + (size_t)r * 128 + csw);
      }
#pragma unroll
      for (int mf = 0; mf < 4; ++mf)
#pragma unroll
        for (int nf = 0; nf < 2; ++nf)
          acc[mf][nf] = __builtin_amdgcn_mfma_f32_16x16x32_fp8_fp8(af[mf], bfr[nf], acc[mf][nf], 0, 0, 0);
    }
    if (nb < TOT) {
      asm volatile("s_waitcnt vmcnt(6)" ::: "memory");
    } else if (t + 1 < TOT) {
      asm volatile("s_waitcnt vmcnt(0)" ::: "memory");
    }
    if (t + 1 < TOT) {
      __builtin_amdgcn_s_barrier();
      __builtin_amdgcn_sched_barrier(0);
    }
    bufc = bufc + 1; if (bufc == 3) bufc = 0;
  }

  int rb = bm * 128 + wr * 64, cb = bn * 64 + wc * 32;
  int rsub = ksel << 2, csub = rof;
  u8* o = p.outR + (size_t)bz * p.batchOutB;
  u8* oT = OTR ? p.outT + (size_t)bz * p.batchOutT : nullptr;
#pragma unroll
  for (int mf = 0; mf < 4; ++mf)
#pragma unroll
    for (int nf = 0; nf < 2; ++nf) {
      int cidx = cb + nf * 16 + csub;
      f32x4 av = acc[mf][nf];
      unsigned w4 = pk4_fp8(av[0] * p.oscR, av[1] * p.oscR,
                            av[2] * p.oscR, av[3] * p.oscR);
#pragma unroll
      for (int r = 0; r < 4; ++r)
        o[(size_t)(rb + mf * 16 + rsub + r) * p.ldOB + cidx] = (u8)(w4 >> (8 * r));
      if constexpr (OTR) {
        *(unsigned*)(oT + (size_t)cidx * p.ldOT + rb + mf * 16 + rsub) = w4;
      }
    }
}

// ---- mixed-precision output GEMM: A,B rows are 2048-byte concat
// [512 bf16 | 512 fp8 x16*64-scaled pair]. BK = 128 bytes, TOT = 16:
// t<8 bf16 MFMA -> accB; t>=8 fp8 MFMA -> acc8. Same staged skeleton. ----
struct GemmMixP {
  const u8 *Ab;              // [8192 rows][ROWB]
  const u8 *Bb;              // [512 rows][ROWB]
  const float* bias;
  float* out;                // f32 [8192][512]
};

__launch_bounds__(256)
__global__ void gemm_mix_k(GemmMixP p) {
  __shared__ u8 As[3][128 * 128];
  __shared__ u8 Bs[3][64 * 128];
  int tid = threadIdx.x;
  int lane = tid & 63;
  int w = tid >> 6;
  int wr = w >> 1, wc = w & 1;
  int bm = blockIdx.x, bn = blockIdx.y;
  int rof = lane & 15, ksel = lane >> 4, sw = lane & 7;
  int wub = (tid & 192) * 16;
  f32x4 accB[4][2] = {};
  f32x4 acc8[4][2] = {};
  const u8* Ag = p.Ab + (size_t)bm * 128 * ROWB;
  const u8* Bg = p.Bb + (size_t)bn * 64 * ROWB;

  auto stage = [&](int t, int buf) {
    int k0 = t * 128;
#pragma unroll
    for (int q = 0; q < 4; ++q) {
      int ch = q * 256 + tid;
      int row = ch >> 3;
      int c8 = (ch & 7) ^ (row & 7);
      gload16(Ag + (size_t)row * ROWB + k0 + c8 * 16, &As[buf][0] + q * 4096 + wub);
    }
#pragma unroll
    for (int q = 0; q < 2; ++q) {
      int ch = q * 256 + tid;
      int row = ch >> 3;
      int c8 = (ch & 7) ^ (row & 7);
      gload16(Bg + (size_t)row * ROWB + k0 + c8 * 16, &Bs[buf][0] + q * 4096 + wub);
    }
  };

  constexpr int TOT = 16;
  stage(0, 0);
  stage(1, 1);
  asm volatile("s_waitcnt vmcnt(6)" ::: "memory");
  __builtin_amdgcn_s_barrier();
  __builtin_amdgcn_sched_barrier(0);

  int bufc = 0;
  for (int t = 0; t < TOT; ++t) {
    int nb = t + 2;
    if (nb < TOT) stage(nb, bufc == 0 ? 2 : bufc - 1);
    const u8* Asb = &As[bufc][0];
    const u8* Bsb = &Bs[bufc][0];
    if (t < 8) {
      // bf16 phase: 64 elems (128 B) per iter, 8 chunks of 16 B
#pragma unroll
      for (int kk = 0; kk < 2; ++kk) {
        int csw = ((kk * 4 + ksel) ^ sw) * 16;
        s16x8 af[4], bfr[2];
#pragma unroll
        for (int mf = 0; mf < 4; ++mf) {
          int r = wr * 64 + mf * 16 + rof;
          af[mf] = *(const s16x8*)(Asb + (size_t)r * 128 + csw);
        }
#pragma unroll
        for (int nf = 0; nf < 2; ++nf) {
          int r = wc * 32 + nf * 16 + rof;
          bfr[nf] = *(const s16x8*)(Bsb + (size_t)r * 128 + csw);
        }
#pragma unroll
        for (int mf = 0; mf < 4; ++mf)
#pragma unroll
          for (int nf = 0; nf < 2; ++nf)
            accB[mf][nf] = __builtin_amdgcn_mfma_f32_16x16x32_bf16(af[mf], bfr[nf], accB[mf][nf], 0, 0, 0);
      }
    } else {
      // fp8 phase: 128 elems per iter
#pragma unroll
      for (int kk = 0; kk < 4; ++kk) {
        int csw = ((2 * kk + (ksel >> 1)) ^ sw) * 16 + (ksel & 1) * 8;
        long af[4], bfr[2];
#pragma unroll
        for (int mf = 0; mf < 4; ++mf) {
          int r = wr * 64 + mf * 16 + rof;
          af[mf] = *(const long*)(Asb + (size_t)r * 128 + csw);
        }
#pragma unroll
        for (int nf = 0; nf < 2; ++nf) {
          int r = wc * 32 + nf * 16 + rof;
          bfr[nf] = *(const long*)(Bsb + (size_t)r * 128 + csw);
        }
#pragma unroll
        for (int mf = 0; mf < 4; ++mf)
#pragma unroll
          for (int nf = 0; nf < 2; ++nf)
            acc8[mf][nf] = __builtin_amdgcn_mfma_f32_16x16x32_fp8_fp8(af[mf], bfr[nf], acc8[mf][nf], 0, 0, 0);
      }
    }
    if (nb < TOT) {
      asm volatile("s_waitcnt vmcnt(6)" ::: "memory");
    } else if (t + 1 < TOT) {
      asm volatile("s_waitcnt vmcnt(0)" ::: "memory");
    }
    if (t + 1 < TOT) {
      __builtin_amdgcn_s_barrier();
      __builtin_amdgcn_sched_barrier(0);
    }
    bufc = bufc + 1; if (bufc == 3) bufc = 0;
  }

  int rb = bm * 128 + wr * 64, cb = bn * 64 + wc * 32;
  int rsub = ksel << 2, csub = rof;
  const float inv = 1.0f / 1024.0f;   // (x16 A) * (x64 B)
#pragma unroll
  for (int nf = 0; nf < 2; ++nf) {
    int cidx = cb + nf * 16 + csub;
    float bv_ = p.bias[cidx];
#pragma unroll
    for (int mf = 0; mf < 4; ++mf)
#pragma unroll
      for (int r = 0; r < 4; ++r) {
        float val = accB[mf][nf][r] + acc8[mf][nf][r] * inv + bv_;
        p.out[(size_t)(rb + mf * 16 + rsub + r) * DOUTC + cidx] = val > 0.f ? val : 0.f;
      }
  }
}

// ---------------- launch ----------------
extern "C" void kernel_launch(void* const* d_in, const int* in_sizes, int n_in,
                              void* d_out, int out_size, void* d_ws, size_t ws_size,
                              hipStream_t stream) {
  const float* X  = (const float*)d_in[0];
  const float* A  = (const float*)d_in[1];
  const float* Wv = (const float*)d_in[2];
  const float* bv = (const float*)d_in[3];
  const float* aw = (const float*)d_in[4];
  const float* ab = (const float*)d_in[5];
  const float* Wk = (const float*)d_in[6];
  const float* bk = (const float*)d_in[7];
  float* out = (float*)d_out;

  char* ws = (char*)d_ws;
  size_t off = 0;
  auto alloc = [&](size_t bytes) -> void* {
    void* p = (void*)(ws + off);
    off = (off + bytes + 255) & ~(size_t)255;
    return p;
  };
  float* u    = (float*)alloc(DI * 4);
  float* v    = (float*)alloc(DI * 4);
  float* cc   = (float*)alloc(256);
  float* bsum = (float*)alloc(DOUTC * 4);
  float* sj   = (float*)alloc((size_t)NB * NN * 4);
  float* si   = (float*)alloc((size_t)NB * NN * 4);
  float* Pj   = (float*)alloc((size_t)8 * NB * NN * 4);
  float* Pi   = (float*)alloc((size_t)8 * NB * NN * 4);
  u8* BkTB  = (u8*)alloc((size_t)DOUTC * ROWB);                // [n][2048 B]
  u8* XbT8  = (u8*)alloc((size_t)NB * DI * NN);                // fp8 X^T
  u8* X123B = (u8*)alloc((size_t)NB * NN * ROWB);              // [b][row][2048 B]
  u8* X1bT8 = (u8*)alloc((size_t)NB * DOUTC * NN);             // fp8 (16*X1)^T
  size_t fixedEnd = off;
  int G = 4;
  while (G > 1 && fixedEnd + (size_t)G * NN * NN > ws_size) G >>= 1;
  u8* Tb8 = (u8*)alloc((size_t)G * NN * NN);                   // fp8 T (x256)

  prep_all<<<3, 256, 0, stream>>>(Wv, aw, bk, bv, ab, u, v, bsum, cc);
  transWk_k<<<dim3(8, 8, 3), 256, 0, stream>>>(Wk, BkTB);
  transX_k<<<dim3(8, 32, NB), 256, 0, stream>>>(X, XbT8, X123B, u, v, Pj, Pi);
  sjsi_red<<<NB * NN / 256, 256, 0, stream>>>(Pj, Pi, sj, si);

  for (int g0 = 0; g0 < NB; g0 += G) {
    tmat_kernel<<<G * NN / 4, 256, 0, stream>>>(A, sj, si, cc, Tb8, g0 * NN);

    // X1 = T @ X : acc = 256*X1. Row fp8 (16*X1) into X123B bytes 1024..1535;
    // transposed fp8 (16*X1) for gemm2's B.
    Gemm8P p1{};
    p1.Ab = Tb8;
    p1.Bb = XbT8 + (size_t)g0 * DI * NN;
    p1.outR = X123B + (size_t)g0 * NN * ROWB + 1024;
    p1.outT = X1bT8 + (size_t)g0 * DOUTC * NN;
    p1.ldA = NN; p1.ldB = NN; p1.ldOB = ROWB; p1.ldOT = NN;
    p1.batchA = (size_t)NN * NN; p1.batchB = (size_t)DI * NN;
    p1.batchOutB = (size_t)NN * ROWB; p1.batchOutT = (size_t)DOUTC * NN;
    p1.oscR = 16.0f / 256.0f;
    gemm8_k<16, true><<<dim3(16, 8, G), 256, 0, stream>>>(p1);

    // X2 = T @ X1 : acc = 256*16*X2 = 4096*X2. Row fp8 (16*X2) into bytes 1536+.
    Gemm8P p2 = p1;
    p2.Bb = X1bT8 + (size_t)g0 * DOUTC * NN;
    p2.outR = X123B + (size_t)g0 * NN * ROWB + 1536;
    p2.outT = nullptr;
    p2.oscR = 16.0f / 4096.0f;
    gemm8_k<16, false><<<dim3(16, 8, G), 256, 0, stream>>>(p2);
  }

  // H = relu( X@W0 (bf16) + (X1@W1 + X2@W2) (fp8) + bsum )
  GemmMixP p3{};
  p3.Ab = X123B; p3.Bb = BkTB; p3.bias = bsum; p3.out = out;
  gemm_mix_k<<<dim3(64, 8, 1), 256, 0, stream>>>(p3);
}

// Round 15
// 105.862 us; speedup vs baseline: 1.5317x; 1.0330x over previous
//
#include <hip/hip_runtime.h>

typedef float f32x4 __attribute__((ext_vector_type(4)));
typedef float f32x16 __attribute__((ext_vector_type(16)));
typedef short s16x8 __attribute__((ext_vector_type(8)));
typedef unsigned short u16;
typedef unsigned char u8;
typedef u16 u16x4v __attribute__((ext_vector_type(4)));
typedef u16 u16x8v __attribute__((ext_vector_type(8)));

#define NB 4
#define NN 2048
#define DI 512
#define DOUTC 512
#define KP 3
#define ROWB 2048   // bytes per concatenated A/B row: 512 bf16 | 512 fp8 | 512 fp8

__device__ __forceinline__ u16 f2b(float f) {
  unsigned u = __builtin_bit_cast(unsigned, f);
  unsigned r = u + 0x7fffu + ((u >> 16) & 1u);
  return (u16)(r >> 16);
}
__device__ __forceinline__ float b2f(u16 h) {
  unsigned u = (unsigned)h << 16;
  return __builtin_bit_cast(float, u);
}
// pack 4 f32 -> 4 fp8 e4m3 (hardware cvt, RNE)
__device__ __forceinline__ unsigned pk4_fp8(float a, float b, float c, float d) {
  int r = __builtin_amdgcn_cvt_pk_fp8_f32(a, b, 0, false);
  r = __builtin_amdgcn_cvt_pk_fp8_f32(c, d, r, true);
  return (unsigned)r;
}

// ---------------- prep (merged): blocks 0-1 -> u,v,bsum ; block 2 -> cc ----
__global__ void prep_all(const float* __restrict__ Wv, const float* __restrict__ aw,
                         const float* __restrict__ bk, const float* __restrict__ bv,
                         const float* __restrict__ ab,
                         float* u, float* v, float* bsum, float* cc) {
  if (blockIdx.x < 2) {
    int c = blockIdx.x * 256 + threadIdx.x;
    float a1 = 0.f, a2 = 0.f;
    const float* row = Wv + (size_t)c * DOUTC;
    for (int d = 0; d < DOUTC; ++d) {
      float w = row[d];
      a1 += w * aw[d];
      a2 += w * aw[DOUTC + d];
    }
    u[c] = a1; v[c] = a2;
    bsum[c] = bk[c] + bk[DOUTC + c] + bk[2 * DOUTC + c];
  } else if (threadIdx.x < 64) {
    int l = threadIdx.x;
    float s = 0.f;
    for (int d = l; d < DOUTC; d += 64) s += bv[d] * (aw[d] + aw[DOUTC + d]);
    for (int o = 32; o; o >>= 1) s += __shfl_down(s, o);
    if (l == 0) cc[0] = s + ab[0];
  }
}

// Wk transpose into BkTB [n=512][ROWB]: z=0 -> bf16 W0^T (bytes 0..1023);
// z=1,2 -> fp8 x64 W{1,2}^T (bytes 1024+/1536+).  grid (8,8,3)
__global__ void transWk_k(const float* __restrict__ in, u8* __restrict__ out) {
  __shared__ u16 tile[64][65];
  int z = blockIdx.z;
  const float* inS = in + (size_t)z * DI * DOUTC;
  int r0 = blockIdx.y * 64, c0 = blockIdx.x * 64;
  int t = threadIdx.x;
#pragma unroll
  for (int p = 0; p < 4; ++p) {
    int g = t + p * 256;
    int r = g >> 4, c4 = (g & 15) << 2;
    f32x4 x = *(const f32x4*)(inS + (size_t)(r0 + r) * DOUTC + c0 + c4);
    tile[r][c4+0] = f2b(x[0]); tile[r][c4+1] = f2b(x[1]);
    tile[r][c4+2] = f2b(x[2]); tile[r][c4+3] = f2b(x[3]);
  }
  __syncthreads();
#pragma unroll
  for (int p = 0; p < 4; ++p) {
    int g = t + p * 256;
    int oc = g >> 4, o4 = (g & 15) << 2;
    if (z == 0) {
      u16x4v wv;
      wv[0] = tile[o4+0][oc]; wv[1] = tile[o4+1][oc];
      wv[2] = tile[o4+2][oc]; wv[3] = tile[o4+3][oc];
      *(u16x4v*)(out + (size_t)(c0 + oc) * ROWB + (size_t)(r0 + o4) * 2) = wv;
    } else {
      unsigned w4 = pk4_fp8(b2f(tile[o4+0][oc]) * 64.f, b2f(tile[o4+1][oc]) * 64.f,
                            b2f(tile[o4+2][oc]) * 64.f, b2f(tile[o4+3][oc]) * 64.f);
      *(unsigned*)(out + (size_t)(c0 + oc) * ROWB + 1024 + (z - 1) * 512 + r0 + o4) = w4;
    }
  }
}

// X transpose (fp8 XbT) + bf16 copy into X123B bytes 0..1023 + fused sj/si dots.
// grid (8, 32, NB)
__global__ void transX_k(const float* __restrict__ X, u8* __restrict__ XbT,
                         u8* __restrict__ X123B,
                         const float* __restrict__ u, const float* __restrict__ v,
                         float* __restrict__ Pj, float* __restrict__ Pi) {
  __shared__ u16 tile[64][65];
  int z = blockIdx.z;
  const float* inS = X + (size_t)z * NN * DI;
  int r0 = blockIdx.y * 64, c0 = blockIdx.x * 64;
  int t = threadIdx.x, cl = t & 15;
  f32x4 u4 = *(const f32x4*)(u + c0 + cl * 4);
  f32x4 v4 = *(const f32x4*)(v + c0 + cl * 4);
#pragma unroll
  for (int p = 0; p < 4; ++p) {
    int g = t + p * 256;
    int r = g >> 4, c4 = cl << 2;
    f32x4 x = *(const f32x4*)(inS + (size_t)(r0 + r) * DI + c0 + c4);
    u16x4v bv4;
    bv4[0] = f2b(x[0]); bv4[1] = f2b(x[1]); bv4[2] = f2b(x[2]); bv4[3] = f2b(x[3]);
    tile[r][c4+0] = bv4[0]; tile[r][c4+1] = bv4[1];
    tile[r][c4+2] = bv4[2]; tile[r][c4+3] = bv4[3];
    *(u16x4v*)(X123B + (size_t)z * NN * ROWB + (size_t)(r0 + r) * ROWB +
               (size_t)(c0 + c4) * 2) = bv4;
    float s1 = x[0]*u4[0] + x[1]*u4[1] + x[2]*u4[2] + x[3]*u4[3];
    float s2 = x[0]*v4[0] + x[1]*v4[1] + x[2]*v4[2] + x[3]*v4[3];
#pragma unroll
    for (int m = 1; m < 16; m <<= 1) {
      s1 += __shfl_xor(s1, m);
      s2 += __shfl_xor(s2, m);
    }
    if (cl == 0) {
      int gr = z * NN + r0 + r;
      Pj[(size_t)blockIdx.x * (NB * NN) + gr] = s1;
      Pi[(size_t)blockIdx.x * (NB * NN) + gr] = s2;
    }
  }
  __syncthreads();
#pragma unroll
  for (int p = 0; p < 4; ++p) {
    int g = t + p * 256;
    int oc = g >> 4, o4 = (g & 15) << 2;
    unsigned w4 = pk4_fp8(b2f(tile[o4+0][oc]), b2f(tile[o4+1][oc]),
                          b2f(tile[o4+2][oc]), b2f(tile[o4+3][oc]));
    *(unsigned*)(XbT + (size_t)z * DI * NN + (size_t)(c0 + oc) * NN + r0 + o4) = w4;
  }
}

// sj[r] = sum_cb Pj[cb][r]  (fixed order -> deterministic)
__global__ void sjsi_red(const float* __restrict__ Pj, const float* __restrict__ Pi,
                         float* __restrict__ sj, float* __restrict__ si) {
  int r = blockIdx.x * 256 + threadIdx.x;
  float s1 = 0.f, s2 = 0.f;
#pragma unroll
  for (int cb = 0; cb < 8; ++cb) {
    s1 += Pj[(size_t)cb * (NB * NN) + r];
    s2 += Pi[(size_t)cb * (NB * NN) + r];
  }
  sj[r] = s1; si[r] = s2;
}

// one wave per row: denom + transition. T stored as fp8 e4m3 scaled x256.
__global__ void tmat_kernel(const float* __restrict__ Aa, const float* __restrict__ sj,
                            const float* __restrict__ si, const float* __restrict__ ccp,
                            u8* __restrict__ T, int rowbase) {
  int wid = threadIdx.x >> 6, lane = threadIdx.x & 63;
  int lr = blockIdx.x * 4 + wid;
  int gi = rowbase + lr;
  int b = gi >> 11;
  float siv = si[gi] + ccp[0];
  const f32x4* Arow = (const f32x4*)(Aa + (size_t)gi * NN);
  const f32x4* sjr = (const f32x4*)(sj + (size_t)b * NN);
  f32x4 al[8];
  float sum = 0.f;
#pragma unroll
  for (int t = 0; t < 8; ++t) {
    int f4 = lane + 64 * t;
    f32x4 a = Arow[f4];
    f32x4 s = sjr[f4];
#pragma unroll
    for (int j = 0; j < 4; ++j) {
      float e = s[j] + siv;
      e = e > 0.f ? e : 0.2f * e;
      al[t][j] = a[j] * __expf(e);
      sum += al[t][j];
    }
  }
#pragma unroll
  for (int o = 1; o < 64; o <<= 1) sum += __shfl_xor(sum, o);
  float rs = 256.0f / (sum + 1e-12f);
  u8* Trow = T + (size_t)lr * NN;
#pragma unroll
  for (int t = 0; t < 8; ++t) {
    int f4 = lane + 64 * t;
    unsigned w4 = pk4_fp8(al[t][0] * rs, al[t][1] * rs, al[t][2] * rs, al[t][3] * rs);
    *(unsigned*)(Trow + 4 * f4) = w4;
  }
}

__device__ __forceinline__ void gload16(const void* g, const void* l) {
  __builtin_amdgcn_global_load_lds((const __attribute__((address_space(1))) void*)g,
                                   (__attribute__((address_space(3))) void*)l, 16, 0, 0);
}

// ---- fp8 T-GEMM: R13/R14 HW-validated staging/sync skeleton; compute body
// switched to v_mfma_f32_32x32x16_fp8_fp8 (half the LDS fragment-read bytes:
// per kk, lane reads 8B of A rows lane&31 (+32) and B row lane&31 at
// k = kk*16 + (lane>>5)*8).  C layout (m74/m101-verified):
// col=lane&31, row=(reg&3)+8*(reg>>2)+4*(lane>>5). ----
struct Gemm8P {
  const u8 *Ab;              // M x K fp8, ldA bytes
  const u8 *Bb;              // N x K fp8, ldB bytes
  u8* outR;                  // row-major fp8 out, ldOB bytes
  u8* outT;                  // optional transposed fp8 out, ldOT bytes
  int ldA, ldB, ldOB, ldOT;
  size_t batchA, batchB, batchOutB, batchOutT;
  float oscR;
};

template <int KT, bool OTR>
__launch_bounds__(256)
__global__ void gemm8_k(Gemm8P p) {
  __shared__ u8 As[3][128 * 128];
  __shared__ u8 Bs[3][64 * 128];
  int tid = threadIdx.x;
  int lane = tid & 63;
  int w = tid >> 6;
  int wr = w >> 1, wc = w & 1;
  int bm = blockIdx.x, bn = blockIdx.y, bz = blockIdx.z;
  int wub = (tid & 192) * 16;
  f32x16 acc2[2] = {};
  const u8* Ag = p.Ab + (size_t)bz * p.batchA + (size_t)bm * 128 * p.ldA;
  const u8* Bg = p.Bb + (size_t)bz * p.batchB + (size_t)bn * 64 * p.ldB;

  auto stage = [&](int t, int buf) {
    int k0 = t * 128;
#pragma unroll
    for (int q = 0; q < 4; ++q) {
      int ch = q * 256 + tid;
      int row = ch >> 3;
      int c8 = (ch & 7) ^ (row & 7);
      gload16(Ag + (size_t)row * p.ldA + k0 + c8 * 16, &As[buf][0] + q * 4096 + wub);
    }
#pragma unroll
    for (int q = 0; q < 2; ++q) {
      int ch = q * 256 + tid;
      int row = ch >> 3;
      int c8 = (ch & 7) ^ (row & 7);
      gload16(Bg + (size_t)row * p.ldB + k0 + c8 * 16, &Bs[buf][0] + q * 4096 + wub);
    }
  };

  constexpr int TOT = KT;
  stage(0, 0);
  stage(1, 1);
  asm volatile("s_waitcnt vmcnt(6)" ::: "memory");
  __builtin_amdgcn_s_barrier();
  __builtin_amdgcn_sched_barrier(0);

  // fragment addressing (32x32x16): row = lane&31 (+32 for m=1), 8 bytes at
  // k-chunk kk, intra-chunk offset (lane>>5)*8; swizzle slot = kk ^ (row&7).
  int cl = lane & 31;
  int kb = (lane >> 5) << 3;
  int sw3 = cl & 7;                       // (row&7) identical for ar0/ar1/br
  size_t ar0 = (size_t)(wr * 64 + cl) * 128;
  size_t ar1 = ar0 + 32 * 128;
  size_t br  = (size_t)(wc * 32 + cl) * 128;

  int bufc = 0;
  for (int t = 0; t < TOT; ++t) {
    int nb = t + 2;
    if (nb < TOT) stage(nb, bufc == 0 ? 2 : bufc - 1);
    const u8* Asb = &As[bufc][0];
    const u8* Bsb = &Bs[bufc][0];
#pragma unroll
    for (int kk = 0; kk < 8; ++kk) {
      int co = ((kk ^ sw3) << 4) + kb;
      long a0 = *(const long*)(Asb + ar0 + co);
      long a1 = *(const long*)(Asb + ar1 + co);
      long b0 = *(const long*)(Bsb + br + co);
      acc2[0] = __builtin_amdgcn_mfma_f32_32x32x16_fp8_fp8(a0, b0, acc2[0], 0, 0, 0);
      acc2[1] = __builtin_amdgcn_mfma_f32_32x32x16_fp8_fp8(a1, b0, acc2[1], 0, 0, 0);
    }
    if (nb < TOT) {
      asm volatile("s_waitcnt vmcnt(6)" ::: "memory");
    } else if (t + 1 < TOT) {
      asm volatile("s_waitcnt vmcnt(0)" ::: "memory");
    }
    if (t + 1 < TOT) {
      __builtin_amdgcn_s_barrier();
      __builtin_amdgcn_sched_barrier(0);
    }
    bufc = bufc + 1; if (bufc == 3) bufc = 0;
  }

  int rb = bm * 128 + wr * 64, cb = bn * 64 + wc * 32;
  int rsh = (lane >> 5) << 2;
  int cidx = cb + cl;
  u8* o = p.outR + (size_t)bz * p.batchOutB;
  u8* oT = OTR ? p.outT + (size_t)bz * p.batchOutT : nullptr;
#pragma unroll
  for (int m = 0; m < 2; ++m)
#pragma unroll
    for (int g = 0; g < 4; ++g) {
      int r0 = rb + m * 32 + g * 8 + rsh;
      unsigned w4 = pk4_fp8(acc2[m][4*g+0] * p.oscR, acc2[m][4*g+1] * p.oscR,
                            acc2[m][4*g+2] * p.oscR, acc2[m][4*g+3] * p.oscR);
#pragma unroll
      for (int r = 0; r < 4; ++r)
        o[(size_t)(r0 + r) * p.ldOB + cidx] = (u8)(w4 >> (8 * r));
      if constexpr (OTR) {
        *(unsigned*)(oT + (size_t)cidx * p.ldOT + r0) = w4;
      }
    }
}

// ---- mixed-precision output GEMM: A,B rows are 2048-byte concat
// [512 bf16 | 512 fp8 x16*64-scaled pair]. BK = 128 bytes, TOT = 16:
// t<8 bf16 MFMA -> accB; t>=8 fp8 MFMA -> acc8. Same staged skeleton. ----
struct GemmMixP {
  const u8 *Ab;              // [8192 rows][ROWB]
  const u8 *Bb;              // [512 rows][ROWB]
  const float* bias;
  float* out;                // f32 [8192][512]
};

__launch_bounds__(256)
__global__ void gemm_mix_k(GemmMixP p) {
  __shared__ u8 As[3][128 * 128];
  __shared__ u8 Bs[3][64 * 128];
  int tid = threadIdx.x;
  int lane = tid & 63;
  int w = tid >> 6;
  int wr = w >> 1, wc = w & 1;
  int bm = blockIdx.x, bn = blockIdx.y;
  int rof = lane & 15, ksel = lane >> 4, sw = lane & 7;
  int wub = (tid & 192) * 16;
  f32x4 accB[4][2] = {};
  f32x4 acc8[4][2] = {};
  const u8* Ag = p.Ab + (size_t)bm * 128 * ROWB;
  const u8* Bg = p.Bb + (size_t)bn * 64 * ROWB;

  auto stage = [&](int t, int buf) {
    int k0 = t * 128;
#pragma unroll
    for (int q = 0; q < 4; ++q) {
      int ch = q * 256 + tid;
      int row = ch >> 3;
      int c8 = (ch & 7) ^ (row & 7);
      gload16(Ag + (size_t)row * ROWB + k0 + c8 * 16, &As[buf][0] + q * 4096 + wub);
    }
#pragma unroll
    for (int q = 0; q < 2; ++q) {
      int ch = q * 256 + tid;
      int row = ch >> 3;
      int c8 = (ch & 7) ^ (row & 7);
      gload16(Bg + (size_t)row * ROWB + k0 + c8 * 16, &Bs[buf][0] + q * 4096 + wub);
    }
  };

  constexpr int TOT = 16;
  stage(0, 0);
  stage(1, 1);
  asm volatile("s_waitcnt vmcnt(6)" ::: "memory");
  __builtin_amdgcn_s_barrier();
  __builtin_amdgcn_sched_barrier(0);

  int bufc = 0;
  for (int t = 0; t < TOT; ++t) {
    int nb = t + 2;
    if (nb < TOT) stage(nb, bufc == 0 ? 2 : bufc - 1);
    const u8* Asb = &As[bufc][0];
    const u8* Bsb = &Bs[bufc][0];
    if (t < 8) {
      // bf16 phase: 64 elems (128 B) per iter, 8 chunks of 16 B
#pragma unroll
      for (int kk = 0; kk < 2; ++kk) {
        int csw = ((kk * 4 + ksel) ^ sw) * 16;
        s16x8 af[4], bfr[2];
#pragma unroll
        for (int mf = 0; mf < 4; ++mf) {
          int r = wr * 64 + mf * 16 + rof;
          af[mf] = *(const s16x8*)(Asb + (size_t)r * 128 + csw);
        }
#pragma unroll
        for (int nf = 0; nf < 2; ++nf) {
          int r = wc * 32 + nf * 16 + rof;
          bfr[nf] = *(const s16x8*)(Bsb + (size_t)r * 128 + csw);
        }
#pragma unroll
        for (int mf = 0; mf < 4; ++mf)
#pragma unroll
          for (int nf = 0; nf < 2; ++nf)
            accB[mf][nf] = __builtin_amdgcn_mfma_f32_16x16x32_bf16(af[mf], bfr[nf], accB[mf][nf], 0, 0, 0);
      }
    } else {
      // fp8 phase: 128 elems per iter
#pragma unroll
      for (int kk = 0; kk < 4; ++kk) {
        int csw = ((2 * kk + (ksel >> 1)) ^ sw) * 16 + (ksel & 1) * 8;
        long af[4], bfr[2];
#pragma unroll
        for (int mf = 0; mf < 4; ++mf) {
          int r = wr * 64 + mf * 16 + rof;
          af[mf] = *(const long*)(Asb + (size_t)r * 128 + csw);
        }
#pragma unroll
        for (int nf = 0; nf < 2; ++nf) {
          int r = wc * 32 + nf * 16 + rof;
          bfr[nf] = *(const long*)(Bsb + (size_t)r * 128 + csw);
        }
#pragma unroll
        for (int mf = 0; mf < 4; ++mf)
#pragma unroll
          for (int nf = 0; nf < 2; ++nf)
            acc8[mf][nf] = __builtin_amdgcn_mfma_f32_16x16x32_fp8_fp8(af[mf], bfr[nf], acc8[mf][nf], 0, 0, 0);
      }
    }
    if (nb < TOT) {
      asm volatile("s_waitcnt vmcnt(6)" ::: "memory");
    } else if (t + 1 < TOT) {
      asm volatile("s_waitcnt vmcnt(0)" ::: "memory");
    }
    if (t + 1 < TOT) {
      __builtin_amdgcn_s_barrier();
      __builtin_amdgcn_sched_barrier(0);
    }
    bufc = bufc + 1; if (bufc == 3) bufc = 0;
  }

  int rb = bm * 128 + wr * 64, cb = bn * 64 + wc * 32;
  int rsub = ksel << 2, csub = rof;
  const float inv = 1.0f / 1024.0f;   // (x16 A) * (x64 B)
#pragma unroll
  for (int nf = 0; nf < 2; ++nf) {
    int cidx = cb + nf * 16 + csub;
    float bv_ = p.bias[cidx];
#pragma unroll
    for (int mf = 0; mf < 4; ++mf)
#pragma unroll
      for (int r = 0; r < 4; ++r) {
        float val = accB[mf][nf][r] + acc8[mf][nf][r] * inv + bv_;
        p.out[(size_t)(rb + mf * 16 + rsub + r) * DOUTC + cidx] = val > 0.f ? val : 0.f;
      }
  }
}

// ---------------- launch ----------------
extern "C" void kernel_launch(void* const* d_in, const int* in_sizes, int n_in,
                              void* d_out, int out_size, void* d_ws, size_t ws_size,
                              hipStream_t stream) {
  const float* X  = (const float*)d_in[0];
  const float* A  = (const float*)d_in[1];
  const float* Wv = (const float*)d_in[2];
  const float* bv = (const float*)d_in[3];
  const float* aw = (const float*)d_in[4];
  const float* ab = (const float*)d_in[5];
  const float* Wk = (const float*)d_in[6];
  const float* bk = (const float*)d_in[7];
  float* out = (float*)d_out;

  char* ws = (char*)d_ws;
  size_t off = 0;
  auto alloc = [&](size_t bytes) -> void* {
    void* p = (void*)(ws + off);
    off = (off + bytes + 255) & ~(size_t)255;
    return p;
  };
  float* u    = (float*)alloc(DI * 4);
  float* v    = (float*)alloc(DI * 4);
  float* cc   = (float*)alloc(256);
  float* bsum = (float*)alloc(DOUTC * 4);
  float* sj   = (float*)alloc((size_t)NB * NN * 4);
  float* si   = (float*)alloc((size_t)NB * NN * 4);
  float* Pj   = (float*)alloc((size_t)8 * NB * NN * 4);
  float* Pi   = (float*)alloc((size_t)8 * NB * NN * 4);
  u8* BkTB  = (u8*)alloc((size_t)DOUTC * ROWB);                // [n][2048 B]
  u8* XbT8  = (u8*)alloc((size_t)NB * DI * NN);                // fp8 X^T
  u8* X123B = (u8*)alloc((size_t)NB * NN * ROWB);              // [b][row][2048 B]
  u8* X1bT8 = (u8*)alloc((size_t)NB * DOUTC * NN);             // fp8 (16*X1)^T
  size_t fixedEnd = off;
  int G = 4;
  while (G > 1 && fixedEnd + (size_t)G * NN * NN > ws_size) G >>= 1;
  u8* Tb8 = (u8*)alloc((size_t)G * NN * NN);                   // fp8 T (x256)

  prep_all<<<3, 256, 0, stream>>>(Wv, aw, bk, bv, ab, u, v, bsum, cc);
  transWk_k<<<dim3(8, 8, 3), 256, 0, stream>>>(Wk, BkTB);
  transX_k<<<dim3(8, 32, NB), 256, 0, stream>>>(X, XbT8, X123B, u, v, Pj, Pi);
  sjsi_red<<<NB * NN / 256, 256, 0, stream>>>(Pj, Pi, sj, si);

  for (int g0 = 0; g0 < NB; g0 += G) {
    tmat_kernel<<<G * NN / 4, 256, 0, stream>>>(A, sj, si, cc, Tb8, g0 * NN);

    // X1 = T @ X : acc = 256*X1. Row fp8 (16*X1) into X123B bytes 1024..1535;
    // transposed fp8 (16*X1) for gemm2's B.
    Gemm8P p1{};
    p1.Ab = Tb8;
    p1.Bb = XbT8 + (size_t)g0 * DI * NN;
    p1.outR = X123B + (size_t)g0 * NN * ROWB + 1024;
    p1.outT = X1bT8 + (size_t)g0 * DOUTC * NN;
    p1.ldA = NN; p1.ldB = NN; p1.ldOB = ROWB; p1.ldOT = NN;
    p1.batchA = (size_t)NN * NN; p1.batchB = (size_t)DI * NN;
    p1.batchOutB = (size_t)NN * ROWB; p1.batchOutT = (size_t)DOUTC * NN;
    p1.oscR = 16.0f / 256.0f;
    gemm8_k<16, true><<<dim3(16, 8, G), 256, 0, stream>>>(p1);

    // X2 = T @ X1 : acc = 256*16*X2 = 4096*X2. Row fp8 (16*X2) into bytes 1536+.
    Gemm8P p2 = p1;
    p2.Bb = X1bT8 + (size_t)g0 * DOUTC * NN;
    p2.outR = X123B + (size_t)g0 * NN * ROWB + 1536;
    p2.outT = nullptr;
    p2.oscR = 16.0f / 4096.0f;
    gemm8_k<16, false><<<dim3(16, 8, G), 256, 0, stream>>>(p2);
  }

  // H = relu( X@W0 (bf16) + (X1@W1 + X2@W2) (fp8) + bsum )
  GemmMixP p3{};
  p3.Ab = X123B; p3.Bb = BkTB; p3.bias = bsum; p3.out = out;
  gemm_mix_k<<<dim3(64, 8, 1), 256, 0, stream>>>(p3);
}